// Round 18
// baseline (310.160 us; speedup 1.0000x reference)
//
#include <hip/hip_runtime.h>
#include <math.h>

#define T_DIM 4096
#define D_DIM 1024
#define BS 60
#define NBLK 69
#define NPART 16

typedef __attribute__((ext_vector_type(4))) float f32x4;
typedef __attribute__((ext_vector_type(8))) short short8;
#define MFMAH(a,b,c) __builtin_amdgcn_mfma_f32_16x16x32_f16((a),(b),(c),0,0,0)

static __device__ __forceinline__ ushort f2h(float f) {
  _Float16 h = (_Float16)f;
  return __builtin_bit_cast(ushort, h);
}
static __device__ __forceinline__ float h2f(ushort u) {
  _Float16 h = __builtin_bit_cast(_Float16, u);
  return (float)h;
}

// ---------------------------------------------------------------------------
__global__ __launch_bounds__(256) void k_prep(const float* __restrict__ x,
    ushort* __restrict__ xhi, ushort* __restrict__ xlo, ushort* __restrict__ u) {
  int i = blockIdx.x, tid = threadIdx.x;
  size_t off = (size_t)i * D_DIM + tid * 4;
  float4 v = *reinterpret_cast<const float4*>(x + off);
  float ss = v.x*v.x + v.y*v.y + v.z*v.z + v.w*v.w;
#pragma unroll
  for (int m = 1; m < 64; m <<= 1) ss += __shfl_xor(ss, m);
  __shared__ float sb[4];
  if ((tid & 63) == 0) sb[tid >> 6] = ss;
  __syncthreads();
  float inv = 1.0f / fmaxf(sqrtf(sb[0] + sb[1] + sb[2] + sb[3]), 1e-12f);
  ushort4 h, l, un;
  h.x = f2h(v.x); l.x = f2h(v.x - h2f(h.x)); un.x = f2h(v.x*inv);
  h.y = f2h(v.y); l.y = f2h(v.y - h2f(h.y)); un.y = f2h(v.y*inv);
  h.z = f2h(v.z); l.z = f2h(v.z - h2f(h.z)); un.z = f2h(v.z*inv);
  h.w = f2h(v.w); l.w = f2h(v.w - h2f(h.w)); un.w = f2h(v.w*inv);
  *reinterpret_cast<ushort4*>(xhi + off) = h;
  *reinterpret_cast<ushort4*>(xlo + off) = l;
  *reinterpret_cast<ushort4*>(u + off) = un;
}

__global__ __launch_bounds__(256) void k_wsplit(
    const float* __restrict__ Wq, const float* __restrict__ Wk, const float* __restrict__ Wv,
    ushort* __restrict__ Wqh, ushort* __restrict__ Wkh, ushort* __restrict__ Wvh) {
  int y = blockIdx.y;
  const float* A = (y == 0) ? Wq : (y == 1) ? Wk : Wv;
  ushort* hi = (y == 0) ? Wqh : (y == 1) ? Wkh : Wvh;
  size_t i = ((size_t)blockIdx.x * 256 + threadIdx.x) * 4;
  float4 v = *reinterpret_cast<const float4*>(A + i);
  ushort4 h;
  h.x = f2h(v.x); h.y = f2h(v.y); h.z = f2h(v.z); h.w = f2h(v.w);
  *reinterpret_cast<ushort4*>(hi + i) = h;
}

__global__ __launch_bounds__(256) void k_bsum(const ushort* __restrict__ u, float* __restrict__ Sb) {
  int b = blockIdx.x, tid = threadIdx.x;
  int j0 = b * BS;
  int w = (BS < T_DIM - j0) ? BS : (T_DIM - j0);
  int c = tid * 4;
  float4 acc = {0,0,0,0};
  for (int j = 0; j < w; ++j) {
    ushort4 v = *reinterpret_cast<const ushort4*>(u + (size_t)(j0 + j) * D_DIM + c);
    acc.x += h2f(v.x); acc.y += h2f(v.y); acc.z += h2f(v.z); acc.w += h2f(v.w);
  }
  *reinterpret_cast<float4*>(Sb + (size_t)b * D_DIM + c) = acc;
}

__global__ __launch_bounds__(256) void k_gsum(const float* __restrict__ Sb, float* __restrict__ S) {
  int c = blockIdx.x * 256 + threadIdx.x;
  float s = 0.f;
  for (int b = 0; b < NBLK; ++b) s += Sb[(size_t)b * D_DIM + c];
  S[c] = s;
}

// ---------------------------------------------------------------------------
// Fused QKV GEMM (fp16): Q,K 2-term; V 1-term.  (R11-proven, untouched.)
__global__ __launch_bounds__(256,2) void k_qkv(
    const ushort* __restrict__ xhi, const ushort* __restrict__ xlo,
    const ushort* __restrict__ Wqh, const ushort* __restrict__ Wkh,
    const ushort* __restrict__ Wvh,
    ushort* __restrict__ Qhi, ushort* __restrict__ Qlo,
    ushort* __restrict__ Khi, ushort* __restrict__ Vb) {
  __shared__ __align__(16) ushort lds[28672];
  const int tid = threadIdx.x;
  const int w = tid >> 6, lane = tid & 63;
  const int wr = w >> 1, wc = w & 1;
  const int g = lane >> 4, cl = lane & 15;
  const int i0 = blockIdx.y * 128, j0 = blockIdx.x * 64;

  int adA[4], adB[2];
#pragma unroll
  for (int is = 0; is < 4; ++is) {
    int r = wr*64 + is*16 + cl;
    adA[is] = r*32 + (g ^ ((r >> 1) & 3))*8;
  }
#pragma unroll
  for (int js = 0; js < 2; ++js) {
    int r = wc*32 + js*16 + cl;
    adB[js] = r*32 + (g ^ ((r >> 1) & 3))*8;
  }
  const int ra1 = tid >> 2, ra2 = 64 + (tid >> 2), rbr = tid >> 2;
  const int sa = tid & 3;
  const int wA1 = ra1*32 + (sa ^ ((ra1 >> 1) & 3))*8;
  const int wA2 = ra2*32 + (sa ^ ((ra2 >> 1) & 3))*8;
  const int wB  = rbr*32 + (sa ^ ((rbr >> 1) & 3))*8;
  const size_t gA1 = (size_t)(i0 + ra1) * D_DIM + sa*8;
  const size_t gA2 = (size_t)(i0 + ra2) * D_DIM + sa*8;
  const size_t gB  = (size_t)(j0 + rbr) * D_DIM + sa*8;

  f32x4 accQ[4][2], accK[4][2], accV[4][2];
#pragma unroll
  for (int is = 0; is < 4; ++is)
#pragma unroll
    for (int js = 0; js < 2; ++js) {
      accQ[is][js] = (f32x4){0.f,0.f,0.f,0.f};
      accK[is][js] = (f32x4){0.f,0.f,0.f,0.f};
      accV[is][js] = (f32x4){0.f,0.f,0.f,0.f};
    }

  short8 sXh1 = *reinterpret_cast<const short8*>(xhi + gA1);
  short8 sXh2 = *reinterpret_cast<const short8*>(xhi + gA2);
  short8 sXl1 = *reinterpret_cast<const short8*>(xlo + gA1);
  short8 sXl2 = *reinterpret_cast<const short8*>(xlo + gA2);
  short8 sQh  = *reinterpret_cast<const short8*>(Wqh + gB);
  short8 sKh  = *reinterpret_cast<const short8*>(Wkh + gB);
  short8 sVh  = *reinterpret_cast<const short8*>(Wvh + gB);

  for (int ks = 0; ks < 32; ++ks) {
    const int bofs = (ks & 1) * 14336;
    *reinterpret_cast<short8*>(&lds[bofs + wA1])          = sXh1;
    *reinterpret_cast<short8*>(&lds[bofs + wA2])          = sXh2;
    *reinterpret_cast<short8*>(&lds[bofs + 4096 + wA1])   = sXl1;
    *reinterpret_cast<short8*>(&lds[bofs + 4096 + wA2])   = sXl2;
    *reinterpret_cast<short8*>(&lds[bofs + 8192 + wB])    = sQh;
    *reinterpret_cast<short8*>(&lds[bofs + 10240 + wB])   = sKh;
    *reinterpret_cast<short8*>(&lds[bofs + 12288 + wB])   = sVh;
    __syncthreads();
    short8 aH[4], aL[4], bQh[2], bKh[2], bVh[2];
#pragma unroll
    for (int is = 0; is < 4; ++is) {
      aH[is] = *reinterpret_cast<const short8*>(&lds[bofs + adA[is]]);
      aL[is] = *reinterpret_cast<const short8*>(&lds[bofs + 4096 + adA[is]]);
    }
#pragma unroll
    for (int js = 0; js < 2; ++js) {
      bQh[js] = *reinterpret_cast<const short8*>(&lds[bofs + 8192  + adB[js]]);
      bKh[js] = *reinterpret_cast<const short8*>(&lds[bofs + 10240 + adB[js]]);
      bVh[js] = *reinterpret_cast<const short8*>(&lds[bofs + 12288 + adB[js]]);
    }
    if (ks < 31) {
      const int k0 = (ks + 1) * 32;
      sXh1 = *reinterpret_cast<const short8*>(xhi + gA1 + k0);
      sXh2 = *reinterpret_cast<const short8*>(xhi + gA2 + k0);
      sXl1 = *reinterpret_cast<const short8*>(xlo + gA1 + k0);
      sXl2 = *reinterpret_cast<const short8*>(xlo + gA2 + k0);
      sQh  = *reinterpret_cast<const short8*>(Wqh + gB + k0);
      sKh  = *reinterpret_cast<const short8*>(Wkh + gB + k0);
      sVh  = *reinterpret_cast<const short8*>(Wvh + gB + k0);
    }
#pragma unroll
    for (int js = 0; js < 2; ++js)
#pragma unroll
      for (int is = 0; is < 4; ++is) {
        accQ[is][js] = MFMAH(aH[is], bQh[js], accQ[is][js]);
        accQ[is][js] = MFMAH(aL[is], bQh[js], accQ[is][js]);
        accK[is][js] = MFMAH(aH[is], bKh[js], accK[is][js]);
        accK[is][js] = MFMAH(aL[is], bKh[js], accK[is][js]);
        accV[is][js] = MFMAH(aH[is], bVh[js], accV[is][js]);
      }
  }
#pragma unroll
  for (int is = 0; is < 4; ++is)
#pragma unroll
    for (int js = 0; js < 2; ++js)
#pragma unroll
      for (int a = 0; a < 4; ++a) {
        int gi = i0 + wr*64 + is*16 + g*4 + a;
        int gj = j0 + wc*32 + js*16 + cl;
        size_t o = (size_t)gi*D_DIM + gj;
        float vq = accQ[is][js][a];
        ushort hq = f2h(vq);
        Qhi[o] = hq; Qlo[o] = f2h(vq - h2f(hq));
        Khi[o] = f2h(accK[is][js][a]);
        Vb[o]  = f2h(accV[is][js][a]);
      }
}

// ---------------------------------------------------------------------------
// D = U@U^T (fp16 1-term) -> int8 Dq (d in [-1,1]; q = round(d*127), abs err
// <= 0.004 -> dep err ~1e-6) + diag db stash (fp32).  Pure GEMM, no E dep.
__global__ __launch_bounds__(256,2) void k_D2(
    const ushort* __restrict__ Uh, signed char* __restrict__ Dq,
    float* __restrict__ db) {
  __shared__ __align__(16) ushort lds[24576]; // dbuf 12288: Ui@0 (128x32) | Uj@4096 (256x32)
  const int tid = threadIdx.x;
  const int bid = blockIdx.x;
  const int wg = (bid & 7) * 64 + (bid >> 3);
  const int it = wg >> 4, chunk = wg & 15;
  const int i0 = it * 128, jb = chunk * 256;
  const int w = tid >> 6, lane = tid & 63;
  const int wr = w >> 1, wc = w & 1;
  const int g = lane >> 4, cl = lane & 15;

  int adA[4], adB[8];
#pragma unroll
  for (int is = 0; is < 4; ++is) {
    int r = wr*64 + is*16 + cl;
    adA[is] = r*32 + (g ^ ((r >> 1) & 3))*8;
  }
#pragma unroll
  for (int js = 0; js < 8; ++js) {
    int r = wc*128 + js*16 + cl;
    adB[js] = 4096 + r*32 + (g ^ ((r >> 1) & 3))*8;
  }
  const int ra1 = tid >> 2, ra2 = 64 + (tid >> 2);
  const int sa = tid & 3;
  const int wA1 = ra1*32 + (sa ^ ((ra1 >> 1) & 3))*8;
  const int wA2 = ra2*32 + (sa ^ ((ra2 >> 1) & 3))*8;
  const size_t gA1 = (size_t)(i0 + ra1) * D_DIM + sa*8;
  const size_t gA2 = (size_t)(i0 + ra2) * D_DIM + sa*8;
  int wBo[4];
  size_t gBo[4];
#pragma unroll
  for (int r = 0; r < 4; ++r) {
    int rb = r*64 + (tid >> 2);
    wBo[r] = 4096 + rb*32 + (sa ^ ((rb >> 1) & 3))*8;
    gBo[r] = (size_t)(jb + rb) * D_DIM + sa*8;
  }

  f32x4 acc[4][8];
#pragma unroll
  for (int is = 0; is < 4; ++is)
#pragma unroll
    for (int js = 0; js < 8; ++js) acc[is][js] = (f32x4){0.f,0.f,0.f,0.f};

  short8 sU1 = *reinterpret_cast<const short8*>(Uh + gA1);
  short8 sU2 = *reinterpret_cast<const short8*>(Uh + gA2);
  short8 sV0 = *reinterpret_cast<const short8*>(Uh + gBo[0]);
  short8 sV1 = *reinterpret_cast<const short8*>(Uh + gBo[1]);
  short8 sV2 = *reinterpret_cast<const short8*>(Uh + gBo[2]);
  short8 sV3 = *reinterpret_cast<const short8*>(Uh + gBo[3]);

  for (int ks = 0; ks < 32; ++ks) {
    const int bofs = (ks & 1) * 12288;
    *reinterpret_cast<short8*>(&lds[bofs + wA1])    = sU1;
    *reinterpret_cast<short8*>(&lds[bofs + wA2])    = sU2;
    *reinterpret_cast<short8*>(&lds[bofs + wBo[0]]) = sV0;
    *reinterpret_cast<short8*>(&lds[bofs + wBo[1]]) = sV1;
    *reinterpret_cast<short8*>(&lds[bofs + wBo[2]]) = sV2;
    *reinterpret_cast<short8*>(&lds[bofs + wBo[3]]) = sV3;
    __syncthreads();
    short8 aU[4];
#pragma unroll
    for (int is = 0; is < 4; ++is)
      aU[is] = *reinterpret_cast<const short8*>(&lds[bofs + adA[is]]);
    if (ks < 31) {
      const int k0 = (ks + 1) * 32;
      sU1 = *reinterpret_cast<const short8*>(Uh + gA1 + k0);
      sU2 = *reinterpret_cast<const short8*>(Uh + gA2 + k0);
      sV0 = *reinterpret_cast<const short8*>(Uh + gBo[0] + k0);
      sV1 = *reinterpret_cast<const short8*>(Uh + gBo[1] + k0);
      sV2 = *reinterpret_cast<const short8*>(Uh + gBo[2] + k0);
      sV3 = *reinterpret_cast<const short8*>(Uh + gBo[3] + k0);
    }
#pragma unroll
    for (int js = 0; js < 8; ++js) {
      short8 bU = *reinterpret_cast<const short8*>(&lds[bofs + adB[js]]);
#pragma unroll
      for (int is = 0; is < 4; ++is)
        acc[is][js] = MFMAH(aU[is], bU, acc[is][js]);
    }
  }

  const int iw0 = i0 + wr*64;
  const int blkLo = iw0 / BS, blkHi = (iw0 + 63) / BS;
  const int jw0 = jb + wc*128;
  const bool doDiag = (jw0 < (blkHi+1)*BS) && (jw0 + 128 > blkLo*BS);

#pragma unroll
  for (int is = 0; is < 4; ++is)
#pragma unroll
    for (int a = 0; a < 4; ++a) {
      int gi = i0 + wr*64 + is*16 + g*4 + a;
      int bi = gi / BS;
#pragma unroll
      for (int js = 0; js < 8; ++js) {
        int gj = jb + wc*128 + js*16 + cl;
        float d = acc[is][js][a];
        float dc = fminf(fmaxf(d, -1.f), 1.f);
        Dq[(size_t)gi*T_DIM + gj] = (signed char)(int)rintf(dc * 127.f);
        if (doDiag && gj / BS == bi) {
          int c = gj - bi * BS;
          db[(size_t)gi*64 + c] = d;
        }
      }
    }
}

// ---------------------------------------------------------------------------
// E = Q@K^T (fp16 2-term), E NEVER materialized: epilogue reads Dq (int8),
// computes local-max partial softmax stats (R16-proven epilogue logic with
// R12-proven main loop), eb diag stash, att tile zero-fill.
// NOTE R16: fusing the D GEMM into this K-loop spills (256-reg wall); reading
// precomputed int8 D instead keeps the register budget at R12's level.
__global__ __launch_bounds__(256,2) void k_E2(
    const ushort* __restrict__ Qhi, const ushort* __restrict__ Qlo,
    const ushort* __restrict__ Khi, const signed char* __restrict__ Dq,
    float* __restrict__ att, float* __restrict__ eb,
    float* __restrict__ pm, float* __restrict__ pZ,
    float* __restrict__ pWe, float* __restrict__ pWd) {
  __shared__ __align__(16) ushort lds[32768]; // dbuf 16384: Qhi@0 Qlo@4096 (128x32) | Khi@8192 (256x32)
  __shared__ float stat_s[2][2][64][4];
  const int tid = threadIdx.x;
  const int bid = blockIdx.x;
  const int wg = (bid & 7) * 64 + (bid >> 3);   // XCD-bijective (512 % 8 == 0)
  const int it = wg >> 4, chunk = wg & 15;
  const int i0 = it * 128, jb = chunk * 256;
  const int w = tid >> 6, lane = tid & 63;
  const int wr = w >> 1, wc = w & 1;
  const int g = lane >> 4, cl = lane & 15;

  int adA[4], adB[8];
#pragma unroll
  for (int is = 0; is < 4; ++is) {
    int r = wr*64 + is*16 + cl;
    adA[is] = r*32 + (g ^ ((r >> 1) & 3))*8;
  }
#pragma unroll
  for (int js = 0; js < 8; ++js) {
    int r = wc*128 + js*16 + cl;
    adB[js] = 8192 + r*32 + (g ^ ((r >> 1) & 3))*8;
  }
  const int ra1 = tid >> 2, ra2 = 64 + (tid >> 2);
  const int sa = tid & 3;
  const int wA1 = ra1*32 + (sa ^ ((ra1 >> 1) & 3))*8;
  const int wA2 = ra2*32 + (sa ^ ((ra2 >> 1) & 3))*8;
  const size_t gA1 = (size_t)(i0 + ra1) * D_DIM + sa*8;
  const size_t gA2 = (size_t)(i0 + ra2) * D_DIM + sa*8;
  int wBo[4];
  size_t gBo[4];
#pragma unroll
  for (int r = 0; r < 4; ++r) {
    int rb = r*64 + (tid >> 2);
    wBo[r] = 8192 + rb*32 + (sa ^ ((rb >> 1) & 3))*8;
    gBo[r] = (size_t)(jb + rb) * D_DIM + sa*8;
  }

  f32x4 acc[4][8];
#pragma unroll
  for (int is = 0; is < 4; ++is)
#pragma unroll
    for (int js = 0; js < 8; ++js) acc[is][js] = (f32x4){0.f,0.f,0.f,0.f};

  short8 sQ1 = *reinterpret_cast<const short8*>(Qhi + gA1);
  short8 sQ2 = *reinterpret_cast<const short8*>(Qhi + gA2);
  short8 sq1 = *reinterpret_cast<const short8*>(Qlo + gA1);
  short8 sq2 = *reinterpret_cast<const short8*>(Qlo + gA2);
  short8 sK0 = *reinterpret_cast<const short8*>(Khi + gBo[0]);
  short8 sK1 = *reinterpret_cast<const short8*>(Khi + gBo[1]);
  short8 sK2 = *reinterpret_cast<const short8*>(Khi + gBo[2]);
  short8 sK3 = *reinterpret_cast<const short8*>(Khi + gBo[3]);

  for (int ks = 0; ks < 32; ++ks) {
    const int bofs = (ks & 1) * 16384;
    *reinterpret_cast<short8*>(&lds[bofs + wA1])        = sQ1;
    *reinterpret_cast<short8*>(&lds[bofs + wA2])        = sQ2;
    *reinterpret_cast<short8*>(&lds[bofs + 4096 + wA1]) = sq1;
    *reinterpret_cast<short8*>(&lds[bofs + 4096 + wA2]) = sq2;
    *reinterpret_cast<short8*>(&lds[bofs + wBo[0]])     = sK0;
    *reinterpret_cast<short8*>(&lds[bofs + wBo[1]])     = sK1;
    *reinterpret_cast<short8*>(&lds[bofs + wBo[2]])     = sK2;
    *reinterpret_cast<short8*>(&lds[bofs + wBo[3]])     = sK3;
    __syncthreads();
    short8 aQh[4], aQl[4];
#pragma unroll
    for (int is = 0; is < 4; ++is) {
      aQh[is] = *reinterpret_cast<const short8*>(&lds[bofs + adA[is]]);
      aQl[is] = *reinterpret_cast<const short8*>(&lds[bofs + 4096 + adA[is]]);
    }
    if (ks < 31) {
      const int k0 = (ks + 1) * 32;
      sQ1 = *reinterpret_cast<const short8*>(Qhi + gA1 + k0);
      sQ2 = *reinterpret_cast<const short8*>(Qhi + gA2 + k0);
      sq1 = *reinterpret_cast<const short8*>(Qlo + gA1 + k0);
      sq2 = *reinterpret_cast<const short8*>(Qlo + gA2 + k0);
      sK0 = *reinterpret_cast<const short8*>(Khi + gBo[0] + k0);
      sK1 = *reinterpret_cast<const short8*>(Khi + gBo[1] + k0);
      sK2 = *reinterpret_cast<const short8*>(Khi + gBo[2] + k0);
      sK3 = *reinterpret_cast<const short8*>(Khi + gBo[3] + k0);
    }
#pragma unroll
    for (int js = 0; js < 8; ++js) {
      short8 bK = *reinterpret_cast<const short8*>(&lds[bofs + adB[js]]);
#pragma unroll
      for (int is = 0; is < 4; ++is) {
        acc[is][js] = MFMAH(aQh[is], bK, acc[is][js]);
        acc[is][js] = MFMAH(aQl[is], bK, acc[is][js]);
      }
    }
  }

  // epilogue: local-max partial stats over this 256-col chunk + eb diag stash
  const int iw0 = i0 + wr*64;
  const int blkLo = iw0 / BS, blkHi = (iw0 + 63) / BS;
  const int jw0 = jb + wc*128;
  const bool doDiag = (jw0 < (blkHi+1)*BS) && (jw0 + 128 > blkLo*BS);

#pragma unroll
  for (int is = 0; is < 4; ++is)
#pragma unroll
    for (int a = 0; a < 4; ++a) {
      int gi = i0 + wr*64 + is*16 + g*4 + a;
      int bi = gi / BS;
      float ev[8], dv[8];
#pragma unroll
      for (int js = 0; js < 8; ++js) {
        int gj = jb + wc*128 + js*16 + cl;
        ev[js] = acc[is][js][a];
        dv[js] = (float)(int)Dq[(size_t)gi*T_DIM + gj] * (1.f/127.f);
        if (doDiag && gj / BS == bi) {
          int c = gj - bi * BS;
          eb[(size_t)gi*64 + c] = ev[js];
        }
      }
      float tmax = ev[0];
#pragma unroll
      for (int js = 1; js < 8; ++js) tmax = fmaxf(tmax, ev[js]);
#pragma unroll
      for (int mk = 1; mk < 16; mk <<= 1) tmax = fmaxf(tmax, __shfl_xor(tmax, mk));
      float z = 0.f, we = 0.f, wd = 0.f;
#pragma unroll
      for (int js = 0; js < 8; ++js) {
        float p = __expf(ev[js] - tmax);
        z += p; we += p * ev[js]; wd += p * dv[js];
      }
#pragma unroll
      for (int mk = 1; mk < 16; mk <<= 1) {
        z += __shfl_xor(z, mk); we += __shfl_xor(we, mk); wd += __shfl_xor(wd, mk);
      }
      if (cl == 0) {
        int rl = is*16 + g*4 + a;
        stat_s[wr][wc][rl][0] = tmax;
        stat_s[wr][wc][rl][1] = z;
        stat_s[wr][wc][rl][2] = we;
        stat_s[wr][wc][rl][3] = wd;
      }
    }
  __syncthreads();
  if (tid < 128) {
    int rl = tid & 63, wr2 = tid >> 6;
    float m0 = stat_s[wr2][0][rl][0], Z0 = stat_s[wr2][0][rl][1];
    float We0 = stat_s[wr2][0][rl][2], Wd0 = stat_s[wr2][0][rl][3];
    float m1 = stat_s[wr2][1][rl][0], Z1 = stat_s[wr2][1][rl][1];
    float We1 = stat_s[wr2][1][rl][2], Wd1 = stat_s[wr2][1][rl][3];
    float nm = fmaxf(m0, m1);
    float s0 = __expf(m0 - nm), s1 = __expf(m1 - nm);
    size_t idx = (size_t)chunk*T_DIM + i0 + wr2*64 + rl;
    pm[idx]  = nm;
    pZ[idx]  = Z0*s0 + Z1*s1;
    pWe[idx] = We0*s0 + We1*s1;
    pWd[idx] = Wd0*s0 + Wd1*s1;
  }
  // zero-fill this block's att tile (coalesced float4 rows)
  const int zrow_ = tid >> 6;
  const int zcol  = (tid & 63) * 4;
#pragma unroll
  for (int r = 0; r < 128; r += 4)
    *reinterpret_cast<float4*>(&att[(size_t)(i0 + r + zrow_) * T_DIM + jb + zcol]) =
        (float4){0.f, 0.f, 0.f, 0.f};
}

// ---------------------------------------------------------------------------
// Rescale merge over NPART per-chunk partials (R16-proven); writes mrow/zrow.
__global__ __launch_bounds__(256) void k_merge(const float* __restrict__ pm,
    const float* __restrict__ pZ, const float* __restrict__ pWe, const float* __restrict__ pWd,
    const ushort* __restrict__ Uh, const float* __restrict__ Sg, const float* __restrict__ Sb,
    const float* __restrict__ eb, const float* __restrict__ db,
    float* __restrict__ dep, float* __restrict__ ent,
    float* __restrict__ mrow, float* __restrict__ zrow) {
  int i = blockIdx.x, tid = threadIdx.x;
  float m = pm[i], Z = pZ[i], We = pWe[i], Wd = pWd[i];
  for (int c = 1; c < NPART; ++c) {
    float om = pm[(size_t)c*T_DIM + i], oZ = pZ[(size_t)c*T_DIM + i];
    float oWe = pWe[(size_t)c*T_DIM + i], oWd = pWd[(size_t)c*T_DIM + i];
    float nm = fmaxf(m, om);
    float s1 = __expf(m - nm), s2 = __expf(om - nm);
    Z = Z*s1 + oZ*s2; We = We*s1 + oWe*s2; Wd = Wd*s1 + oWd*s2; m = nm;
  }
  int b = i / BS, j0 = b * BS;
  int w = (BS < T_DIM - j0) ? BS : (T_DIM - j0);
  ushort4 uv = *reinterpret_cast<const ushort4*>(Uh + (size_t)i*D_DIM + tid*4);
  float4 Sv  = *reinterpret_cast<const float4*>(Sg + tid*4);
  float4 Sbv = *reinterpret_cast<const float4*>(Sb + (size_t)b*D_DIM + tid*4);
  float ux = h2f(uv.x), uy = h2f(uv.y), uz = h2f(uv.z), uw = h2f(uv.w);
  float dS  = ux*Sv.x  + uy*Sv.y  + uz*Sv.z  + uw*Sv.w;
  float dSb = ux*Sbv.x + uy*Sbv.y + uz*Sbv.z + uw*Sbv.w;
  float pb = 0.f, pdb = 0.f;
  if (tid < w) {
    float e = eb[(size_t)i*64 + tid], d = db[(size_t)i*64 + tid];
    float p = __expf(e - m);
    pb = p; pdb = p * d;
  }
  float v0 = dS, v1 = dSb, v2 = pb, v3 = pdb;
#pragma unroll
  for (int mk = 1; mk < 64; mk <<= 1) {
    v0 += __shfl_xor(v0, mk); v1 += __shfl_xor(v1, mk);
    v2 += __shfl_xor(v2, mk); v3 += __shfl_xor(v3, mk);
  }
  __shared__ float red[4][4];
  if ((tid & 63) == 0) { int wv = tid >> 6; red[0][wv]=v0; red[1][wv]=v1; red[2][wv]=v2; red[3][wv]=v3; }
  __syncthreads();
  if (tid == 0) {
    float tdS  = red[0][0]+red[0][1]+red[0][2]+red[0][3];
    float tdSb = red[1][0]+red[1][1]+red[1][2]+red[1][3];
    float s1   = red[2][0]+red[2][1]+red[2][2]+red[2][3];
    float s2   = red[3][0]+red[3][1]+red[3][2]+red[3][3];
    float invZ = 1.0f / Z;
    float num = (1.0f - s1*invZ) - (Wd - s2)*invZ;
    float den = (float)(T_DIM - w) - (tdS - tdSb);
    dep[i] = num / den;
    ent[i] = -(We*invZ - m - logf(Z)) / logf((float)T_DIM);
    mrow[i] = m; zrow[i] = Z;
  }
}

__global__ __launch_bounds__(256) void k_entnorm(float* __restrict__ ent) {
  int tid = threadIdx.x;
  float s = 0.f;
  for (int i = tid; i < T_DIM; i += 256) s += fabsf(ent[i]);
#pragma unroll
  for (int mk = 1; mk < 64; mk <<= 1) s += __shfl_xor(s, mk);
  __shared__ float sb[4];
  if ((tid & 63) == 0) sb[tid >> 6] = s;
  __syncthreads();
  float inv = 1.0f / fmaxf(sb[0] + sb[1] + sb[2] + sb[3], 1e-12f);
  for (int i = tid; i < T_DIM; i += 256) ent[i] *= inv;
}

__global__ __launch_bounds__(256) void k_repack(const float* __restrict__ Wout, ushort* __restrict__ Wob) {
  int o = blockIdx.x;
  for (int k = threadIdx.x; k < 1024; k += 256)
    Wob[(size_t)o * 1024 + k] = f2h(Wout[(size_t)o * 1026 + k]);
}

// diag att write (att already zeroed by k_E2) + y = att_win @ V.  (R15-proven.)
__global__ __launch_bounds__(256) void k_atty(const float* __restrict__ eb, const float* __restrict__ mrow,
    const float* __restrict__ zrow, const float* __restrict__ dep, const ushort* __restrict__ Vb,
    float* __restrict__ att, ushort* __restrict__ Ybf) {
  const int b  = blockIdx.x;
  const int cc = blockIdx.y & 3, rt = blockIdx.y >> 2;
  const int j0 = b * BS;
  const int w  = (BS < T_DIM - j0) ? BS : (T_DIM - j0);
  const int r0 = rt * 12;
  __shared__ float wl[12][BS + 1];
  __shared__ __align__(16) ushort vs[BS][256];
  const int tid = threadIdx.x;
  for (int idx = tid; idx < 12 * w; idx += 256) {
    int rr = idx / w, c = idx - rr * w;
    float val = 0.f;
    if (r0 + rr < w) {
      int gi = j0 + r0 + rr;
      val = __expf(eb[(size_t)gi * 64 + c] - mrow[gi]) / zrow[gi] + dep[j0 + c];
      if (cc == 0) att[(size_t)gi * T_DIM + j0 + c] = val;
    }
    wl[rr][c] = val;
  }
  const int ccol = cc * 256;
  for (int idx = tid; idx < w * 32; idx += 256) {
    int j = idx >> 5, s = idx & 31;
    *reinterpret_cast<short8*>(&vs[j][s * 8]) =
        *reinterpret_cast<const short8*>(&Vb[(size_t)(j0 + j) * D_DIM + ccol + s * 8]);
  }
  __syncthreads();
  float acc[12];
#pragma unroll
  for (int rr = 0; rr < 12; ++rr) acc[rr] = 0.f;
  for (int j = 0; j < w; ++j) {
    float v = h2f(vs[j][tid]);
#pragma unroll
    for (int rr = 0; rr < 12; ++rr)
      acc[rr] = fmaf(wl[rr][j], v, acc[rr]);
  }
#pragma unroll
  for (int rr = 0; rr < 12; ++rr)
    if (r0 + rr < w)
      Ybf[(size_t)(j0 + r0 + rr) * D_DIM + ccol + tid] = f2h(acc[rr]);
}

// ---------------------------------------------------------------------------
__global__ __launch_bounds__(256,4) void k_final(
    const ushort* __restrict__ Ybf, const ushort* __restrict__ Wob,
    const float* __restrict__ Wout, const float* __restrict__ ent,
    const float* __restrict__ dep, float* __restrict__ yout) {
  __shared__ ushort ldsB[8192];  // 2 x 4096
  const int tid = threadIdx.x;
  const int w = tid >> 6, lane = tid & 63;
  const int wr = w >> 1, wc = w & 1;
  const int g = lane >> 4, cl = lane & 15;
  const int i0 = blockIdx.y * 64, j0 = blockIdx.x * 64;
  f32x4 acc[2][2];
#pragma unroll
  for (int a = 0; a < 2; ++a)
#pragma unroll
    for (int b = 0; b < 2; ++b) acc[a][b] = (f32x4){0.f,0.f,0.f,0.f};
  const int ar0 = i0 + wr*32 + cl;

  const int r1 = tid >> 3, c1 = tid & 7;
  const int r2 = (tid + 256) >> 3, c2 = (tid + 256) & 7;
  const int lo1 = r1*64 + (c1 ^ (r1 & 7))*8;
  const int lo2 = r2*64 + (c2 ^ (r2 & 7))*8;
  const size_t gB1 = (size_t)(j0 + r1) * D_DIM + c1*8;
  const size_t gB2 = (size_t)(j0 + r2) * D_DIM + c2*8;

  short8 sB1 = *reinterpret_cast<const short8*>(Wob + gB1);
  short8 sB2 = *reinterpret_cast<const short8*>(Wob + gB2);
  short8 aY[2][2];
#pragma unroll
  for (int is = 0; is < 2; ++is)
#pragma unroll
    for (int h = 0; h < 2; ++h)
      aY[is][h] = *reinterpret_cast<const short8*>(Ybf + (size_t)(ar0 + is*16) * D_DIM + (h*4+g)*8);

  for (int ks = 0; ks < 16; ++ks) {
    const int bofs = (ks & 1) * 4096;
    *reinterpret_cast<short8*>(&ldsB[bofs + lo1]) = sB1;
    *reinterpret_cast<short8*>(&ldsB[bofs + lo2]) = sB2;
    __syncthreads();
    short8 aC[2][2];
#pragma unroll
    for (int is = 0; is < 2; ++is)
#pragma unroll
      for (int h = 0; h < 2; ++h) aC[is][h] = aY[is][h];
    if (ks < 15) {
      const int k0 = (ks + 1) * 64;
      sB1 = *reinterpret_cast<const short8*>(Wob + gB1 + k0);
      sB2 = *reinterpret_cast<const short8*>(Wob + gB2 + k0);
#pragma unroll
      for (int is = 0; is < 2; ++is)
#pragma unroll
        for (int h = 0; h < 2; ++h)
          aY[is][h] = *reinterpret_cast<const short8*>(Ybf + (size_t)(ar0 + is*16) * D_DIM + k0 + (h*4+g)*8);
    }
#pragma unroll
    for (int h = 0; h < 2; ++h)
#pragma unroll
      for (int js = 0; js < 2; ++js) {
        const int br = wc*32 + js*16 + cl;
        short8 bW = *reinterpret_cast<const short8*>(&ldsB[bofs + br*64 + ((h*4+g) ^ (br & 7))*8]);
#pragma unroll
        for (int is = 0; is < 2; ++is)
          acc[is][js] = MFMAH(aC[is][h], bW, acc[is][js]);
      }
  }
  float w1[2], w2[2];
#pragma unroll
  for (int js = 0; js < 2; ++js) {
    int gj = j0 + wc*32 + js*16 + cl;
    w1[js] = Wout[(size_t)gj * 1026 + 1024];
    w2[js] = Wout[(size_t)gj * 1026 + 1025];
  }
#pragma unroll
  for (int is = 0; is < 2; ++is)
#pragma unroll
    for (int a = 0; a < 4; ++a) {
      int gi = i0 + wr*32 + is*16 + g*4 + a;
      float e = ent[gi], d = dep[gi];
#pragma unroll
      for (int js = 0; js < 2; ++js) {
        int gj = j0 + wc*32 + js*16 + cl;
        yout[(size_t)gi * D_DIM + gj] = acc[is][js][a] + e * w1[js] + d * w2[js];
      }
    }
}

// ---------------------------------------------------------------------------
extern "C" void kernel_launch(void* const* d_in, const int* in_sizes, int n_in,
                              void* d_out, int out_size, void* d_ws, size_t ws_size,
                              hipStream_t stream) {
  const float* x    = (const float*)d_in[0];
  const float* Wk   = (const float*)d_in[1];
  const float* Wq   = (const float*)d_in[2];
  const float* Wv   = (const float*)d_in[3];
  const float* Wout = (const float*)d_in[4];
  float* out = (float*)d_out;
  char* wsb  = (char*)d_ws;

  ushort* Uh   = (ushort*)(wsb + 0);            // 8 MB (fp16)
  ushort* Vb   = (ushort*)(wsb + 8388608);      // 8 MB
  ushort* Wqh  = (ushort*)(wsb + 16777216);     // 2 MB (dead after k_qkv)
  ushort* Wkh  = (ushort*)(wsb + 18874368);     // 2 MB (dead after k_qkv)
  ushort* Wvh  = (ushort*)(wsb + 20971520);     // 2 MB (dead after k_qkv)
  ushort* Ybf  = (ushort*)(wsb + 23068672);     // 8 MB (written by k_atty)
  ushort* Wob  = (ushort*)(wsb + 31457280);     // 2 MB (written by k_repack)
  // Dq (int8 D matrix, 16 MB) aliases Wqh..Wob: written by k_D2 (after k_qkv),
  // consumed by k_E2 (before k_repack/k_atty).  Timeline audited.
  signed char* Dq = (signed char*)(wsb + 16777216);
  ushort* Khi  = (ushort*)(wsb + 33554432);     // 8 MB
  ushort* xhi  = (ushort*)(wsb + 41943040);     // 8 MB
  ushort* xlo  = (ushort*)(wsb + 50331648);     // 8 MB
  // x-zone aliases (valid after k_qkv)
  float*  eb   = (float*)(wsb + 41943040);      // 1 MB
  float*  db   = (float*)(wsb + 42991616);      // 1 MB
  float*  pZ   = (float*)(wsb + 44040192);      // 0.5 MB each (16 partials)
  float*  pWe  = (float*)(wsb + 44564480);
  float*  pWd  = (float*)(wsb + 45088768);
  float*  pm   = (float*)(wsb + 45613056);
  float*  Sb   = (float*)(wsb + 46137344);      // 283 KB
  float*  Sg   = (float*)(wsb + 46428160);      // 4 KB
  float*  mrow = (float*)(wsb + 46432256);      // 16 KB each
  float*  zrow = (float*)(wsb + 46448640);
  float*  ent  = (float*)(wsb + 46465024);
  float*  dep  = (float*)(wsb + 46481408);

  float* yout = out;                               // [4096][1024]
  float* att  = out + (size_t)T_DIM * D_DIM;       // [4096][4096]
  ushort* Qhi = (ushort*)yout;                     // Q splits live in yout until k_E2 done
  ushort* Qlo = Qhi + 4194304;

  k_prep<<<T_DIM, 256, 0, stream>>>(x, xhi, xlo, Uh);
  k_wsplit<<<dim3(1024, 3), 256, 0, stream>>>(Wq, Wk, Wv, Wqh, Wkh, Wvh);
  k_qkv<<<dim3(16, 32), 256, 0, stream>>>(xhi, xlo, Wqh, Wkh, Wvh,
                                          Qhi, Qlo, Khi, Vb);
  k_bsum<<<NBLK, 256, 0, stream>>>(Uh, Sb);
  k_gsum<<<4, 256, 0, stream>>>(Sb, Sg);

  k_D2<<<512, 256, 0, stream>>>(Uh, Dq, db);
  k_E2<<<512, 256, 0, stream>>>(Qhi, Qlo, Khi, Dq, att, eb, pm, pZ, pWe, pWd);
  k_merge<<<T_DIM, 256, 0, stream>>>(pm, pZ, pWe, pWd, Uh, Sg, Sb, eb, db, dep, ent, mrow, zrow);
  k_entnorm<<<1, 256, 0, stream>>>(ent);

  k_repack<<<1024, 256, 0, stream>>>(Wout, Wob);
  k_atty<<<dim3(NBLK, 20), 256, 0, stream>>>(eb, mrow, zrow, dep, Vb, att, Ybf);
  k_final<<<dim3(16, 64), 256, 0, stream>>>(Ybf, Wob, Wout, ent, dep, yout);
}

// Round 19
// 293.851 us; speedup vs baseline: 1.0555x; 1.0555x over previous
//
#include <hip/hip_runtime.h>
#include <math.h>

#define T_DIM 4096
#define D_DIM 1024
#define BS 60
#define NBLK 69
#define NPART 16

typedef __attribute__((ext_vector_type(4))) float f32x4;
typedef __attribute__((ext_vector_type(8))) short short8;
#define MFMAH(a,b,c) __builtin_amdgcn_mfma_f32_16x16x32_f16((a),(b),(c),0,0,0)

static __device__ __forceinline__ ushort f2h(float f) {
  _Float16 h = (_Float16)f;
  return __builtin_bit_cast(ushort, h);
}
static __device__ __forceinline__ float h2f(ushort u) {
  _Float16 h = __builtin_bit_cast(_Float16, u);
  return (float)h;
}

// ---------------------------------------------------------------------------
__global__ __launch_bounds__(256) void k_prep(const float* __restrict__ x,
    ushort* __restrict__ xhi, ushort* __restrict__ xlo, ushort* __restrict__ u) {
  int i = blockIdx.x, tid = threadIdx.x;
  size_t off = (size_t)i * D_DIM + tid * 4;
  float4 v = *reinterpret_cast<const float4*>(x + off);
  float ss = v.x*v.x + v.y*v.y + v.z*v.z + v.w*v.w;
#pragma unroll
  for (int m = 1; m < 64; m <<= 1) ss += __shfl_xor(ss, m);
  __shared__ float sb[4];
  if ((tid & 63) == 0) sb[tid >> 6] = ss;
  __syncthreads();
  float inv = 1.0f / fmaxf(sqrtf(sb[0] + sb[1] + sb[2] + sb[3]), 1e-12f);
  ushort4 h, l, un;
  h.x = f2h(v.x); l.x = f2h(v.x - h2f(h.x)); un.x = f2h(v.x*inv);
  h.y = f2h(v.y); l.y = f2h(v.y - h2f(h.y)); un.y = f2h(v.y*inv);
  h.z = f2h(v.z); l.z = f2h(v.z - h2f(h.z)); un.z = f2h(v.z*inv);
  h.w = f2h(v.w); l.w = f2h(v.w - h2f(h.w)); un.w = f2h(v.w*inv);
  *reinterpret_cast<ushort4*>(xhi + off) = h;
  *reinterpret_cast<ushort4*>(xlo + off) = l;
  *reinterpret_cast<ushort4*>(u + off) = un;
}

__global__ __launch_bounds__(256) void k_wsplit(
    const float* __restrict__ Wq, const float* __restrict__ Wk, const float* __restrict__ Wv,
    ushort* __restrict__ Wqh, ushort* __restrict__ Wkh, ushort* __restrict__ Wvh) {
  int y = blockIdx.y;
  const float* A = (y == 0) ? Wq : (y == 1) ? Wk : Wv;
  ushort* hi = (y == 0) ? Wqh : (y == 1) ? Wkh : Wvh;
  size_t i = ((size_t)blockIdx.x * 256 + threadIdx.x) * 4;
  float4 v = *reinterpret_cast<const float4*>(A + i);
  ushort4 h;
  h.x = f2h(v.x); h.y = f2h(v.y); h.z = f2h(v.z); h.w = f2h(v.w);
  *reinterpret_cast<ushort4*>(hi + i) = h;
}

__global__ __launch_bounds__(256) void k_bsum(const ushort* __restrict__ u, float* __restrict__ Sb) {
  int b = blockIdx.x, tid = threadIdx.x;
  int j0 = b * BS;
  int w = (BS < T_DIM - j0) ? BS : (T_DIM - j0);
  int c = tid * 4;
  float4 acc = {0,0,0,0};
  for (int j = 0; j < w; ++j) {
    ushort4 v = *reinterpret_cast<const ushort4*>(u + (size_t)(j0 + j) * D_DIM + c);
    acc.x += h2f(v.x); acc.y += h2f(v.y); acc.z += h2f(v.z); acc.w += h2f(v.w);
  }
  *reinterpret_cast<float4*>(Sb + (size_t)b * D_DIM + c) = acc;
}

__global__ __launch_bounds__(256) void k_gsum(const float* __restrict__ Sb, float* __restrict__ S) {
  int c = blockIdx.x * 256 + threadIdx.x;
  float s = 0.f;
  for (int b = 0; b < NBLK; ++b) s += Sb[(size_t)b * D_DIM + c];
  S[c] = s;
}

// ---------------------------------------------------------------------------
// Fused QKV GEMM (fp16): Q,K 2-term; V 1-term.  (R11-proven, untouched.)
__global__ __launch_bounds__(256,2) void k_qkv(
    const ushort* __restrict__ xhi, const ushort* __restrict__ xlo,
    const ushort* __restrict__ Wqh, const ushort* __restrict__ Wkh,
    const ushort* __restrict__ Wvh,
    ushort* __restrict__ Qhi, ushort* __restrict__ Qlo,
    ushort* __restrict__ Khi, ushort* __restrict__ Vb) {
  __shared__ __align__(16) ushort lds[28672];
  const int tid = threadIdx.x;
  const int w = tid >> 6, lane = tid & 63;
  const int wr = w >> 1, wc = w & 1;
  const int g = lane >> 4, cl = lane & 15;
  const int i0 = blockIdx.y * 128, j0 = blockIdx.x * 64;

  int adA[4], adB[2];
#pragma unroll
  for (int is = 0; is < 4; ++is) {
    int r = wr*64 + is*16 + cl;
    adA[is] = r*32 + (g ^ ((r >> 1) & 3))*8;
  }
#pragma unroll
  for (int js = 0; js < 2; ++js) {
    int r = wc*32 + js*16 + cl;
    adB[js] = r*32 + (g ^ ((r >> 1) & 3))*8;
  }
  const int ra1 = tid >> 2, ra2 = 64 + (tid >> 2), rbr = tid >> 2;
  const int sa = tid & 3;
  const int wA1 = ra1*32 + (sa ^ ((ra1 >> 1) & 3))*8;
  const int wA2 = ra2*32 + (sa ^ ((ra2 >> 1) & 3))*8;
  const int wB  = rbr*32 + (sa ^ ((rbr >> 1) & 3))*8;
  const size_t gA1 = (size_t)(i0 + ra1) * D_DIM + sa*8;
  const size_t gA2 = (size_t)(i0 + ra2) * D_DIM + sa*8;
  const size_t gB  = (size_t)(j0 + rbr) * D_DIM + sa*8;

  f32x4 accQ[4][2], accK[4][2], accV[4][2];
#pragma unroll
  for (int is = 0; is < 4; ++is)
#pragma unroll
    for (int js = 0; js < 2; ++js) {
      accQ[is][js] = (f32x4){0.f,0.f,0.f,0.f};
      accK[is][js] = (f32x4){0.f,0.f,0.f,0.f};
      accV[is][js] = (f32x4){0.f,0.f,0.f,0.f};
    }

  short8 sXh1 = *reinterpret_cast<const short8*>(xhi + gA1);
  short8 sXh2 = *reinterpret_cast<const short8*>(xhi + gA2);
  short8 sXl1 = *reinterpret_cast<const short8*>(xlo + gA1);
  short8 sXl2 = *reinterpret_cast<const short8*>(xlo + gA2);
  short8 sQh  = *reinterpret_cast<const short8*>(Wqh + gB);
  short8 sKh  = *reinterpret_cast<const short8*>(Wkh + gB);
  short8 sVh  = *reinterpret_cast<const short8*>(Wvh + gB);

  for (int ks = 0; ks < 32; ++ks) {
    const int bofs = (ks & 1) * 14336;
    *reinterpret_cast<short8*>(&lds[bofs + wA1])          = sXh1;
    *reinterpret_cast<short8*>(&lds[bofs + wA2])          = sXh2;
    *reinterpret_cast<short8*>(&lds[bofs + 4096 + wA1])   = sXl1;
    *reinterpret_cast<short8*>(&lds[bofs + 4096 + wA2])   = sXl2;
    *reinterpret_cast<short8*>(&lds[bofs + 8192 + wB])    = sQh;
    *reinterpret_cast<short8*>(&lds[bofs + 10240 + wB])   = sKh;
    *reinterpret_cast<short8*>(&lds[bofs + 12288 + wB])   = sVh;
    __syncthreads();
    short8 aH[4], aL[4], bQh[2], bKh[2], bVh[2];
#pragma unroll
    for (int is = 0; is < 4; ++is) {
      aH[is] = *reinterpret_cast<const short8*>(&lds[bofs + adA[is]]);
      aL[is] = *reinterpret_cast<const short8*>(&lds[bofs + 4096 + adA[is]]);
    }
#pragma unroll
    for (int js = 0; js < 2; ++js) {
      bQh[js] = *reinterpret_cast<const short8*>(&lds[bofs + 8192  + adB[js]]);
      bKh[js] = *reinterpret_cast<const short8*>(&lds[bofs + 10240 + adB[js]]);
      bVh[js] = *reinterpret_cast<const short8*>(&lds[bofs + 12288 + adB[js]]);
    }
    if (ks < 31) {
      const int k0 = (ks + 1) * 32;
      sXh1 = *reinterpret_cast<const short8*>(xhi + gA1 + k0);
      sXh2 = *reinterpret_cast<const short8*>(xhi + gA2 + k0);
      sXl1 = *reinterpret_cast<const short8*>(xlo + gA1 + k0);
      sXl2 = *reinterpret_cast<const short8*>(xlo + gA2 + k0);
      sQh  = *reinterpret_cast<const short8*>(Wqh + gB + k0);
      sKh  = *reinterpret_cast<const short8*>(Wkh + gB + k0);
      sVh  = *reinterpret_cast<const short8*>(Wvh + gB + k0);
    }
#pragma unroll
    for (int js = 0; js < 2; ++js)
#pragma unroll
      for (int is = 0; is < 4; ++is) {
        accQ[is][js] = MFMAH(aH[is], bQh[js], accQ[is][js]);
        accQ[is][js] = MFMAH(aL[is], bQh[js], accQ[is][js]);
        accK[is][js] = MFMAH(aH[is], bKh[js], accK[is][js]);
        accK[is][js] = MFMAH(aL[is], bKh[js], accK[is][js]);
        accV[is][js] = MFMAH(aH[is], bVh[js], accV[is][js]);
      }
  }
#pragma unroll
  for (int is = 0; is < 4; ++is)
#pragma unroll
    for (int js = 0; js < 2; ++js)
#pragma unroll
      for (int a = 0; a < 4; ++a) {
        int gi = i0 + wr*64 + is*16 + g*4 + a;
        int gj = j0 + wc*32 + js*16 + cl;
        size_t o = (size_t)gi*D_DIM + gj;
        float vq = accQ[is][js][a];
        ushort hq = f2h(vq);
        Qhi[o] = hq; Qlo[o] = f2h(vq - h2f(hq));
        Khi[o] = f2h(accK[is][js][a]);
        Vb[o]  = f2h(accV[is][js][a]);
      }
}

// ---------------------------------------------------------------------------
// E = Q@K^T (fp16 2-term) -> fp32 + row-max partials.  (R12-proven.)
// NOTE R16: fusing D into this K-loop spills (256-reg wall) -> 2.4x slower.
// NOTE R18: consuming int8-compressed D in the epilogue is a byte-gather,
// also slower.  The E round-trip through HBM is the least-bad structure.
__global__ __launch_bounds__(256,2) void k_E(
    const ushort* __restrict__ Qhi, const ushort* __restrict__ Qlo,
    const ushort* __restrict__ Khi,
    float* __restrict__ E, float* __restrict__ pm) {
  __shared__ __align__(16) ushort lds[32768]; // dbuf 16384: Qhi@0 Qlo@4096 (128x32) | Khi@8192 (256x32)
  __shared__ float stat_s[2][2][64];
  const int tid = threadIdx.x;
  const int bid = blockIdx.x;
  const int wg = (bid & 7) * 64 + (bid >> 3);   // XCD-bijective (512 % 8 == 0)
  const int it = wg >> 4, chunk = wg & 15;
  const int i0 = it * 128, jb = chunk * 256;
  const int w = tid >> 6, lane = tid & 63;
  const int wr = w >> 1, wc = w & 1;
  const int g = lane >> 4, cl = lane & 15;

  int adA[4], adB[8];
#pragma unroll
  for (int is = 0; is < 4; ++is) {
    int r = wr*64 + is*16 + cl;
    adA[is] = r*32 + (g ^ ((r >> 1) & 3))*8;
  }
#pragma unroll
  for (int js = 0; js < 8; ++js) {
    int r = wc*128 + js*16 + cl;
    adB[js] = 8192 + r*32 + (g ^ ((r >> 1) & 3))*8;
  }
  const int ra1 = tid >> 2, ra2 = 64 + (tid >> 2);
  const int sa = tid & 3;
  const int wA1 = ra1*32 + (sa ^ ((ra1 >> 1) & 3))*8;
  const int wA2 = ra2*32 + (sa ^ ((ra2 >> 1) & 3))*8;
  const size_t gA1 = (size_t)(i0 + ra1) * D_DIM + sa*8;
  const size_t gA2 = (size_t)(i0 + ra2) * D_DIM + sa*8;
  int wBo[4];
  size_t gBo[4];
#pragma unroll
  for (int r = 0; r < 4; ++r) {
    int rb = r*64 + (tid >> 2);
    wBo[r] = 8192 + rb*32 + (sa ^ ((rb >> 1) & 3))*8;
    gBo[r] = (size_t)(jb + rb) * D_DIM + sa*8;
  }

  f32x4 acc[4][8];
#pragma unroll
  for (int is = 0; is < 4; ++is)
#pragma unroll
    for (int js = 0; js < 8; ++js) acc[is][js] = (f32x4){0.f,0.f,0.f,0.f};

  short8 sQ1 = *reinterpret_cast<const short8*>(Qhi + gA1);
  short8 sQ2 = *reinterpret_cast<const short8*>(Qhi + gA2);
  short8 sq1 = *reinterpret_cast<const short8*>(Qlo + gA1);
  short8 sq2 = *reinterpret_cast<const short8*>(Qlo + gA2);
  short8 sK0 = *reinterpret_cast<const short8*>(Khi + gBo[0]);
  short8 sK1 = *reinterpret_cast<const short8*>(Khi + gBo[1]);
  short8 sK2 = *reinterpret_cast<const short8*>(Khi + gBo[2]);
  short8 sK3 = *reinterpret_cast<const short8*>(Khi + gBo[3]);

  for (int ks = 0; ks < 32; ++ks) {
    const int bofs = (ks & 1) * 16384;
    *reinterpret_cast<short8*>(&lds[bofs + wA1])        = sQ1;
    *reinterpret_cast<short8*>(&lds[bofs + wA2])        = sQ2;
    *reinterpret_cast<short8*>(&lds[bofs + 4096 + wA1]) = sq1;
    *reinterpret_cast<short8*>(&lds[bofs + 4096 + wA2]) = sq2;
    *reinterpret_cast<short8*>(&lds[bofs + wBo[0]])     = sK0;
    *reinterpret_cast<short8*>(&lds[bofs + wBo[1]])     = sK1;
    *reinterpret_cast<short8*>(&lds[bofs + wBo[2]])     = sK2;
    *reinterpret_cast<short8*>(&lds[bofs + wBo[3]])     = sK3;
    __syncthreads();
    short8 aQh[4], aQl[4];
#pragma unroll
    for (int is = 0; is < 4; ++is) {
      aQh[is] = *reinterpret_cast<const short8*>(&lds[bofs + adA[is]]);
      aQl[is] = *reinterpret_cast<const short8*>(&lds[bofs + 4096 + adA[is]]);
    }
    if (ks < 31) {
      const int k0 = (ks + 1) * 32;
      sQ1 = *reinterpret_cast<const short8*>(Qhi + gA1 + k0);
      sQ2 = *reinterpret_cast<const short8*>(Qhi + gA2 + k0);
      sq1 = *reinterpret_cast<const short8*>(Qlo + gA1 + k0);
      sq2 = *reinterpret_cast<const short8*>(Qlo + gA2 + k0);
      sK0 = *reinterpret_cast<const short8*>(Khi + gBo[0] + k0);
      sK1 = *reinterpret_cast<const short8*>(Khi + gBo[1] + k0);
      sK2 = *reinterpret_cast<const short8*>(Khi + gBo[2] + k0);
      sK3 = *reinterpret_cast<const short8*>(Khi + gBo[3] + k0);
    }
#pragma unroll
    for (int js = 0; js < 8; ++js) {
      short8 bK = *reinterpret_cast<const short8*>(&lds[bofs + adB[js]]);
#pragma unroll
      for (int is = 0; is < 4; ++is) {
        acc[is][js] = MFMAH(aQh[is], bK, acc[is][js]);
        acc[is][js] = MFMAH(aQl[is], bK, acc[is][js]);
      }
    }
  }
  // store E + row-max partials
#pragma unroll
  for (int is = 0; is < 4; ++is)
#pragma unroll
    for (int a = 0; a < 4; ++a) {
      int gi = i0 + wr*64 + is*16 + g*4 + a;
      float mx = -3.0e38f;
#pragma unroll
      for (int js = 0; js < 8; ++js) {
        float e = acc[is][js][a];
        E[(size_t)gi*T_DIM + jb + wc*128 + js*16 + cl] = e;
        mx = fmaxf(mx, e);
      }
#pragma unroll
      for (int mk = 1; mk < 16; mk <<= 1) mx = fmaxf(mx, __shfl_xor(mx, mk));
      if (cl == 0) stat_s[wr][wc][is*16 + g*4 + a] = mx;
    }
  __syncthreads();
  if (tid < 128) {
    int rl = tid & 63, wr2 = tid >> 6;
    pm[(size_t)chunk*T_DIM + i0 + wr2*64 + rl] =
        fmaxf(stat_s[wr2][0][rl], stat_s[wr2][1][rl]);
  }
}

__global__ __launch_bounds__(256) void k_rowmax(const float* __restrict__ pm, float* __restrict__ mrow) {
  int i = blockIdx.x * 256 + threadIdx.x;
  float m = -3.0e38f;
  for (int c = 0; c < NPART; ++c) m = fmaxf(m, pm[(size_t)c*T_DIM + i]);
  mrow[i] = m;
}

// ---------------------------------------------------------------------------
// D = U@U^T (fp16 1-term) + p=exp(e-m) stats + diag stash + tile zero-fill.
__global__ __launch_bounds__(256,2) void k_D(
    const ushort* __restrict__ Uh, float* __restrict__ E,
    const float* __restrict__ mrow,
    float* __restrict__ eb, float* __restrict__ db,
    float* __restrict__ pZ, float* __restrict__ pWe, float* __restrict__ pWd) {
  __shared__ __align__(16) ushort lds[24576]; // dbuf 12288: Ui@0 (128x32) | Uj@4096 (256x32)
  __shared__ float stat_s[2][2][64][3];
  const int tid = threadIdx.x;
  const int bid = blockIdx.x;
  const int wg = (bid & 7) * 64 + (bid >> 3);
  const int it = wg >> 4, chunk = wg & 15;
  const int i0 = it * 128, jb = chunk * 256;
  const int w = tid >> 6, lane = tid & 63;
  const int wr = w >> 1, wc = w & 1;
  const int g = lane >> 4, cl = lane & 15;

  int adA[4], adB[8];
#pragma unroll
  for (int is = 0; is < 4; ++is) {
    int r = wr*64 + is*16 + cl;
    adA[is] = r*32 + (g ^ ((r >> 1) & 3))*8;
  }
#pragma unroll
  for (int js = 0; js < 8; ++js) {
    int r = wc*128 + js*16 + cl;
    adB[js] = 4096 + r*32 + (g ^ ((r >> 1) & 3))*8;
  }
  const int ra1 = tid >> 2, ra2 = 64 + (tid >> 2);
  const int sa = tid & 3;
  const int wA1 = ra1*32 + (sa ^ ((ra1 >> 1) & 3))*8;
  const int wA2 = ra2*32 + (sa ^ ((ra2 >> 1) & 3))*8;
  const size_t gA1 = (size_t)(i0 + ra1) * D_DIM + sa*8;
  const size_t gA2 = (size_t)(i0 + ra2) * D_DIM + sa*8;
  int wBo[4];
  size_t gBo[4];
#pragma unroll
  for (int r = 0; r < 4; ++r) {
    int rb = r*64 + (tid >> 2);
    wBo[r] = 4096 + rb*32 + (sa ^ ((rb >> 1) & 3))*8;
    gBo[r] = (size_t)(jb + rb) * D_DIM + sa*8;
  }

  f32x4 acc[4][8];
#pragma unroll
  for (int is = 0; is < 4; ++is)
#pragma unroll
    for (int js = 0; js < 8; ++js) acc[is][js] = (f32x4){0.f,0.f,0.f,0.f};

  short8 sU1 = *reinterpret_cast<const short8*>(Uh + gA1);
  short8 sU2 = *reinterpret_cast<const short8*>(Uh + gA2);
  short8 sV0 = *reinterpret_cast<const short8*>(Uh + gBo[0]);
  short8 sV1 = *reinterpret_cast<const short8*>(Uh + gBo[1]);
  short8 sV2 = *reinterpret_cast<const short8*>(Uh + gBo[2]);
  short8 sV3 = *reinterpret_cast<const short8*>(Uh + gBo[3]);

  for (int ks = 0; ks < 32; ++ks) {
    const int bofs = (ks & 1) * 12288;
    *reinterpret_cast<short8*>(&lds[bofs + wA1])    = sU1;
    *reinterpret_cast<short8*>(&lds[bofs + wA2])    = sU2;
    *reinterpret_cast<short8*>(&lds[bofs + wBo[0]]) = sV0;
    *reinterpret_cast<short8*>(&lds[bofs + wBo[1]]) = sV1;
    *reinterpret_cast<short8*>(&lds[bofs + wBo[2]]) = sV2;
    *reinterpret_cast<short8*>(&lds[bofs + wBo[3]]) = sV3;
    __syncthreads();
    short8 aU[4];
#pragma unroll
    for (int is = 0; is < 4; ++is)
      aU[is] = *reinterpret_cast<const short8*>(&lds[bofs + adA[is]]);
    if (ks < 31) {
      const int k0 = (ks + 1) * 32;
      sU1 = *reinterpret_cast<const short8*>(Uh + gA1 + k0);
      sU2 = *reinterpret_cast<const short8*>(Uh + gA2 + k0);
      sV0 = *reinterpret_cast<const short8*>(Uh + gBo[0] + k0);
      sV1 = *reinterpret_cast<const short8*>(Uh + gBo[1] + k0);
      sV2 = *reinterpret_cast<const short8*>(Uh + gBo[2] + k0);
      sV3 = *reinterpret_cast<const short8*>(Uh + gBo[3] + k0);
    }
#pragma unroll
    for (int js = 0; js < 8; ++js) {
      short8 bU = *reinterpret_cast<const short8*>(&lds[bofs + adB[js]]);
#pragma unroll
      for (int is = 0; is < 4; ++is)
        acc[is][js] = MFMAH(aU[is], bU, acc[is][js]);
    }
  }

  // epilogue: p = exp(e - m), plain-sum partials + diag stash
  const int iw0 = i0 + wr*64;
  const int blkLo = iw0 / BS, blkHi = (iw0 + 63) / BS;
  const int jw0 = jb + wc*128;
  const bool doDiag = (jw0 < (blkHi+1)*BS) && (jw0 + 128 > blkLo*BS);

#pragma unroll
  for (int is = 0; is < 4; ++is)
#pragma unroll
    for (int a = 0; a < 4; ++a) {
      int gi = i0 + wr*64 + is*16 + g*4 + a;
      int bi = gi / BS;
      float m = mrow[gi];
      float z = 0.f, we = 0.f, wd = 0.f;
#pragma unroll
      for (int js = 0; js < 8; ++js) {
        int gj = jb + wc*128 + js*16 + cl;
        float e = E[(size_t)gi*T_DIM + gj];
        float d = acc[is][js][a];
        float p = __expf(e - m);
        z += p; we += p*e; wd += p*d;
        if (doDiag && gj / BS == bi) {
          int c = gj - bi * BS;
          eb[(size_t)gi*64 + c] = e;
          db[(size_t)gi*64 + c] = d;
        }
      }
#pragma unroll
      for (int mk = 1; mk < 16; mk <<= 1) {
        z += __shfl_xor(z, mk); we += __shfl_xor(we, mk); wd += __shfl_xor(wd, mk);
      }
      if (cl == 0) {
        int rl = is*16 + g*4 + a;
        stat_s[wr][wc][rl][0] = z;
        stat_s[wr][wc][rl][1] = we;
        stat_s[wr][wc][rl][2] = wd;
      }
    }
  __syncthreads();   // all E reads complete block-wide
  if (tid < 128) {
    int rl = tid & 63, wr2 = tid >> 6;
    size_t idx = (size_t)chunk*T_DIM + i0 + wr2*64 + rl;
    pZ[idx]  = stat_s[wr2][0][rl][0] + stat_s[wr2][1][rl][0];
    pWe[idx] = stat_s[wr2][0][rl][1] + stat_s[wr2][1][rl][1];
    pWd[idx] = stat_s[wr2][0][rl][2] + stat_s[wr2][1][rl][2];
  }
  // zero-fill this block's att tile (coalesced float4 rows)
  const int zrow_ = tid >> 6;
  const int zcol  = (tid & 63) * 4;
#pragma unroll
  for (int r = 0; r < 128; r += 4)
    *reinterpret_cast<float4*>(&E[(size_t)(i0 + r + zrow_) * T_DIM + jb + zcol]) =
        (float4){0.f, 0.f, 0.f, 0.f};
}

// ---------------------------------------------------------------------------
__global__ __launch_bounds__(256) void k_merge(const float* __restrict__ pZ,
    const float* __restrict__ pWe, const float* __restrict__ pWd,
    const float* __restrict__ mrow,
    const ushort* __restrict__ Uh, const float* __restrict__ Sg, const float* __restrict__ Sb,
    const float* __restrict__ eb, const float* __restrict__ db,
    float* __restrict__ dep, float* __restrict__ ent, float* __restrict__ zrow) {
  int i = blockIdx.x, tid = threadIdx.x;
  float m = mrow[i];
  float Z = 0.f, We = 0.f, Wd = 0.f;
  for (int c = 0; c < NPART; ++c) {
    Z  += pZ [(size_t)c*T_DIM + i];
    We += pWe[(size_t)c*T_DIM + i];
    Wd += pWd[(size_t)c*T_DIM + i];
  }
  int b = i / BS, j0 = b * BS;
  int w = (BS < T_DIM - j0) ? BS : (T_DIM - j0);
  ushort4 uv = *reinterpret_cast<const ushort4*>(Uh + (size_t)i*D_DIM + tid*4);
  float4 Sv  = *reinterpret_cast<const float4*>(Sg + tid*4);
  float4 Sbv = *reinterpret_cast<const float4*>(Sb + (size_t)b*D_DIM + tid*4);
  float ux = h2f(uv.x), uy = h2f(uv.y), uz = h2f(uv.z), uw = h2f(uv.w);
  float dS  = ux*Sv.x  + uy*Sv.y  + uz*Sv.z  + uw*Sv.w;
  float dSb = ux*Sbv.x + uy*Sbv.y + uz*Sbv.z + uw*Sbv.w;
  float pb = 0.f, pdb = 0.f;
  if (tid < w) {
    float e = eb[(size_t)i*64 + tid], d = db[(size_t)i*64 + tid];
    float p = __expf(e - m);
    pb = p; pdb = p * d;
  }
  float v0 = dS, v1 = dSb, v2 = pb, v3 = pdb;
#pragma unroll
  for (int mk = 1; mk < 64; mk <<= 1) {
    v0 += __shfl_xor(v0, mk); v1 += __shfl_xor(v1, mk);
    v2 += __shfl_xor(v2, mk); v3 += __shfl_xor(v3, mk);
  }
  __shared__ float red[4][4];
  if ((tid & 63) == 0) { int wv = tid >> 6; red[0][wv]=v0; red[1][wv]=v1; red[2][wv]=v2; red[3][wv]=v3; }
  __syncthreads();
  if (tid == 0) {
    float tdS  = red[0][0]+red[0][1]+red[0][2]+red[0][3];
    float tdSb = red[1][0]+red[1][1]+red[1][2]+red[1][3];
    float s1   = red[2][0]+red[2][1]+red[2][2]+red[2][3];
    float s2   = red[3][0]+red[3][1]+red[3][2]+red[3][3];
    float invZ = 1.0f / Z;
    float num = (1.0f - s1*invZ) - (Wd - s2)*invZ;
    float den = (float)(T_DIM - w) - (tdS - tdSb);
    dep[i] = num / den;
    ent[i] = -(We*invZ - m - logf(Z)) / logf((float)T_DIM);
    zrow[i] = Z;
  }
}

__global__ __launch_bounds__(256) void k_entnorm(float* __restrict__ ent) {
  int tid = threadIdx.x;
  float s = 0.f;
  for (int i = tid; i < T_DIM; i += 256) s += fabsf(ent[i]);
#pragma unroll
  for (int mk = 1; mk < 64; mk <<= 1) s += __shfl_xor(s, mk);
  __shared__ float sb[4];
  if ((tid & 63) == 0) sb[tid >> 6] = s;
  __syncthreads();
  float inv = 1.0f / fmaxf(sb[0] + sb[1] + sb[2] + sb[3], 1e-12f);
  for (int i = tid; i < T_DIM; i += 256) ent[i] *= inv;
}

__global__ __launch_bounds__(256) void k_repack(const float* __restrict__ Wout, ushort* __restrict__ Wob) {
  int o = blockIdx.x;
  for (int k = threadIdx.x; k < 1024; k += 256)
    Wob[(size_t)o * 1024 + k] = f2h(Wout[(size_t)o * 1026 + k]);
}

// diag att write (att already zeroed by k_D) + y = att_win @ V.  (R15-proven.)
__global__ __launch_bounds__(256) void k_atty(const float* __restrict__ eb, const float* __restrict__ mrow,
    const float* __restrict__ zrow, const float* __restrict__ dep, const ushort* __restrict__ Vb,
    float* __restrict__ att, ushort* __restrict__ Ybf) {
  const int b  = blockIdx.x;
  const int cc = blockIdx.y & 3, rt = blockIdx.y >> 2;
  const int j0 = b * BS;
  const int w  = (BS < T_DIM - j0) ? BS : (T_DIM - j0);
  const int r0 = rt * 12;
  __shared__ float wl[12][BS + 1];
  __shared__ __align__(16) ushort vs[BS][256];
  const int tid = threadIdx.x;
  for (int idx = tid; idx < 12 * w; idx += 256) {
    int rr = idx / w, c = idx - rr * w;
    float val = 0.f;
    if (r0 + rr < w) {
      int gi = j0 + r0 + rr;
      val = __expf(eb[(size_t)gi * 64 + c] - mrow[gi]) / zrow[gi] + dep[j0 + c];
      if (cc == 0) att[(size_t)gi * T_DIM + j0 + c] = val;
    }
    wl[rr][c] = val;
  }
  const int ccol = cc * 256;
  for (int idx = tid; idx < w * 32; idx += 256) {
    int j = idx >> 5, s = idx & 31;
    *reinterpret_cast<short8*>(&vs[j][s * 8]) =
        *reinterpret_cast<const short8*>(&Vb[(size_t)(j0 + j) * D_DIM + ccol + s * 8]);
  }
  __syncthreads();
  float acc[12];
#pragma unroll
  for (int rr = 0; rr < 12; ++rr) acc[rr] = 0.f;
  for (int j = 0; j < w; ++j) {
    float v = h2f(vs[j][tid]);
#pragma unroll
    for (int rr = 0; rr < 12; ++rr)
      acc[rr] = fmaf(wl[rr][j], v, acc[rr]);
  }
#pragma unroll
  for (int rr = 0; rr < 12; ++rr)
    if (r0 + rr < w)
      Ybf[(size_t)(j0 + r0 + rr) * D_DIM + ccol + tid] = f2h(acc[rr]);
}

// ---------------------------------------------------------------------------
__global__ __launch_bounds__(256,4) void k_final(
    const ushort* __restrict__ Ybf, const ushort* __restrict__ Wob,
    const float* __restrict__ Wout, const float* __restrict__ ent,
    const float* __restrict__ dep, float* __restrict__ yout) {
  __shared__ ushort ldsB[8192];  // 2 x 4096
  const int tid = threadIdx.x;
  const int w = tid >> 6, lane = tid & 63;
  const int wr = w >> 1, wc = w & 1;
  const int g = lane >> 4, cl = lane & 15;
  const int i0 = blockIdx.y * 64, j0 = blockIdx.x * 64;
  f32x4 acc[2][2];
#pragma unroll
  for (int a = 0; a < 2; ++a)
#pragma unroll
    for (int b = 0; b < 2; ++b) acc[a][b] = (f32x4){0.f,0.f,0.f,0.f};
  const int ar0 = i0 + wr*32 + cl;

  const int r1 = tid >> 3, c1 = tid & 7;
  const int r2 = (tid + 256) >> 3, c2 = (tid + 256) & 7;
  const int lo1 = r1*64 + (c1 ^ (r1 & 7))*8;
  const int lo2 = r2*64 + (c2 ^ (r2 & 7))*8;
  const size_t gB1 = (size_t)(j0 + r1) * D_DIM + c1*8;
  const size_t gB2 = (size_t)(j0 + r2) * D_DIM + c2*8;

  short8 sB1 = *reinterpret_cast<const short8*>(Wob + gB1);
  short8 sB2 = *reinterpret_cast<const short8*>(Wob + gB2);
  short8 aY[2][2];
#pragma unroll
  for (int is = 0; is < 2; ++is)
#pragma unroll
    for (int h = 0; h < 2; ++h)
      aY[is][h] = *reinterpret_cast<const short8*>(Ybf + (size_t)(ar0 + is*16) * D_DIM + (h*4+g)*8);

  for (int ks = 0; ks < 16; ++ks) {
    const int bofs = (ks & 1) * 4096;
    *reinterpret_cast<short8*>(&ldsB[bofs + lo1]) = sB1;
    *reinterpret_cast<short8*>(&ldsB[bofs + lo2]) = sB2;
    __syncthreads();
    short8 aC[2][2];
#pragma unroll
    for (int is = 0; is < 2; ++is)
#pragma unroll
      for (int h = 0; h < 2; ++h) aC[is][h] = aY[is][h];
    if (ks < 15) {
      const int k0 = (ks + 1) * 64;
      sB1 = *reinterpret_cast<const short8*>(Wob + gB1 + k0);
      sB2 = *reinterpret_cast<const short8*>(Wob + gB2 + k0);
#pragma unroll
      for (int is = 0; is < 2; ++is)
#pragma unroll
        for (int h = 0; h < 2; ++h)
          aY[is][h] = *reinterpret_cast<const short8*>(Ybf + (size_t)(ar0 + is*16) * D_DIM + k0 + (h*4+g)*8);
    }
#pragma unroll
    for (int h = 0; h < 2; ++h)
#pragma unroll
      for (int js = 0; js < 2; ++js) {
        const int br = wc*32 + js*16 + cl;
        short8 bW = *reinterpret_cast<const short8*>(&ldsB[bofs + br*64 + ((h*4+g) ^ (br & 7))*8]);
#pragma unroll
        for (int is = 0; is < 2; ++is)
          acc[is][js] = MFMAH(aC[is][h], bW, acc[is][js]);
      }
  }
  float w1[2], w2[2];
#pragma unroll
  for (int js = 0; js < 2; ++js) {
    int gj = j0 + wc*32 + js*16 + cl;
    w1[js] = Wout[(size_t)gj * 1026 + 1024];
    w2[js] = Wout[(size_t)gj * 1026 + 1025];
  }
#pragma unroll
  for (int is = 0; is < 2; ++is)
#pragma unroll
    for (int a = 0; a < 4; ++a) {
      int gi = i0 + wr*32 + is*16 + g*4 + a;
      float e = ent[gi], d = dep[gi];
#pragma unroll
      for (int js = 0; js < 2; ++js) {
        int gj = j0 + wc*32 + js*16 + cl;
        yout[(size_t)gi * D_DIM + gj] = acc[is][js][a] + e * w1[js] + d * w2[js];
      }
    }
}

// ---------------------------------------------------------------------------
extern "C" void kernel_launch(void* const* d_in, const int* in_sizes, int n_in,
                              void* d_out, int out_size, void* d_ws, size_t ws_size,
                              hipStream_t stream) {
  const float* x    = (const float*)d_in[0];
  const float* Wk   = (const float*)d_in[1];
  const float* Wq   = (const float*)d_in[2];
  const float* Wv   = (const float*)d_in[3];
  const float* Wout = (const float*)d_in[4];
  float* out = (float*)d_out;
  char* wsb  = (char*)d_ws;

  ushort* Uh   = (ushort*)(wsb + 0);            // 8 MB (fp16)
  ushort* Vb   = (ushort*)(wsb + 8388608);      // 8 MB
  ushort* Wqh  = (ushort*)(wsb + 16777216);     // 2 MB
  ushort* Wkh  = (ushort*)(wsb + 18874368);     // 2 MB
  ushort* Wvh  = (ushort*)(wsb + 20971520);     // 2 MB
  ushort* Ybf  = (ushort*)(wsb + 23068672);     // 8 MB
  ushort* Wob  = (ushort*)(wsb + 31457280);     // 2 MB
  ushort* Khi  = (ushort*)(wsb + 33554432);     // 8 MB
  ushort* xhi  = (ushort*)(wsb + 41943040);     // 8 MB
  ushort* xlo  = (ushort*)(wsb + 50331648);     // 8 MB
  // x-zone aliases (valid after k_qkv)
  float*  eb   = (float*)(wsb + 41943040);      // 1 MB
  float*  db   = (float*)(wsb + 42991616);      // 1 MB
  float*  pZ   = (float*)(wsb + 44040192);      // 0.5 MB each
  float*  pWe  = (float*)(wsb + 44564480);
  float*  pWd  = (float*)(wsb + 45088768);
  float*  pm   = (float*)(wsb + 45613056);
  float*  Sb   = (float*)(wsb + 46137344);      // 283 KB
  float*  Sg   = (float*)(wsb + 46428160);      // 4 KB
  float*  mrow = (float*)(wsb + 46432256);      // 16 KB each
  float*  zrow = (float*)(wsb + 46448640);
  float*  ent  = (float*)(wsb + 46465024);
  float*  dep  = (float*)(wsb + 46481408);

  float* yout = out;                               // [4096][1024]
  float* att  = out + (size_t)T_DIM * D_DIM;       // [4096][4096] = E scratch then att
  ushort* Qhi = (ushort*)yout;                     // Q splits live in yout until k_E done
  ushort* Qlo = Qhi + 4194304;
  float*  E   = att;

  k_prep<<<T_DIM, 256, 0, stream>>>(x, xhi, xlo, Uh);
  k_wsplit<<<dim3(1024, 3), 256, 0, stream>>>(Wq, Wk, Wv, Wqh, Wkh, Wvh);
  k_qkv<<<dim3(16, 32), 256, 0, stream>>>(xhi, xlo, Wqh, Wkh, Wvh,
                                          Qhi, Qlo, Khi, Vb);
  k_bsum<<<NBLK, 256, 0, stream>>>(Uh, Sb);
  k_gsum<<<4, 256, 0, stream>>>(Sb, Sg);

  k_E<<<512, 256, 0, stream>>>(Qhi, Qlo, Khi, E, pm);
  k_rowmax<<<16, 256, 0, stream>>>(pm, mrow);
  k_D<<<512, 256, 0, stream>>>(Uh, E, mrow, eb, db, pZ, pWe, pWd);
  k_merge<<<T_DIM, 256, 0, stream>>>(pZ, pWe, pWd, mrow, Uh, Sg, Sb, eb, db, dep, ent, zrow);
  k_entnorm<<<1, 256, 0, stream>>>(ent);

  k_repack<<<1024, 256, 0, stream>>>(Wout, Wob);
  k_atty<<<dim3(NBLK, 20), 256, 0, stream>>>(eb, mrow, zrow, dep, Vb, att, Ybf);
  k_final<<<dim3(16, 64), 256, 0, stream>>>(Ybf, Wob, Wout, ent, dep, yout);
}

// Round 20
// 291.217 us; speedup vs baseline: 1.0650x; 1.0090x over previous
//
#include <hip/hip_runtime.h>
#include <math.h>

#define T_DIM 4096
#define D_DIM 1024
#define BS 60
#define NBLK 69
#define NPART 16

typedef __attribute__((ext_vector_type(4))) float f32x4;
typedef __attribute__((ext_vector_type(8))) short short8;
#define MFMAH(a,b,c) __builtin_amdgcn_mfma_f32_16x16x32_f16((a),(b),(c),0,0,0)

static __device__ __forceinline__ ushort f2h(float f) {
  _Float16 h = (_Float16)f;
  return __builtin_bit_cast(ushort, h);
}
static __device__ __forceinline__ float h2f(ushort u) {
  _Float16 h = __builtin_bit_cast(_Float16, u);
  return (float)h;
}

// ---------------------------------------------------------------------------
__global__ __launch_bounds__(256) void k_prep(const float* __restrict__ x,
    ushort* __restrict__ xhi, ushort* __restrict__ xlo, ushort* __restrict__ u) {
  int i = blockIdx.x, tid = threadIdx.x;
  size_t off = (size_t)i * D_DIM + tid * 4;
  float4 v = *reinterpret_cast<const float4*>(x + off);
  float ss = v.x*v.x + v.y*v.y + v.z*v.z + v.w*v.w;
#pragma unroll
  for (int m = 1; m < 64; m <<= 1) ss += __shfl_xor(ss, m);
  __shared__ float sb[4];
  if ((tid & 63) == 0) sb[tid >> 6] = ss;
  __syncthreads();
  float inv = 1.0f / fmaxf(sqrtf(sb[0] + sb[1] + sb[2] + sb[3]), 1e-12f);
  ushort4 h, l, un;
  h.x = f2h(v.x); l.x = f2h(v.x - h2f(h.x)); un.x = f2h(v.x*inv);
  h.y = f2h(v.y); l.y = f2h(v.y - h2f(h.y)); un.y = f2h(v.y*inv);
  h.z = f2h(v.z); l.z = f2h(v.z - h2f(h.z)); un.z = f2h(v.z*inv);
  h.w = f2h(v.w); l.w = f2h(v.w - h2f(h.w)); un.w = f2h(v.w*inv);
  *reinterpret_cast<ushort4*>(xhi + off) = h;
  *reinterpret_cast<ushort4*>(xlo + off) = l;
  *reinterpret_cast<ushort4*>(u + off) = un;
}

__global__ __launch_bounds__(256) void k_wsplit(
    const float* __restrict__ Wq, const float* __restrict__ Wk, const float* __restrict__ Wv,
    ushort* __restrict__ Wqh, ushort* __restrict__ Wkh, ushort* __restrict__ Wvh) {
  int y = blockIdx.y;
  const float* A = (y == 0) ? Wq : (y == 1) ? Wk : Wv;
  ushort* hi = (y == 0) ? Wqh : (y == 1) ? Wkh : Wvh;
  size_t i = ((size_t)blockIdx.x * 256 + threadIdx.x) * 4;
  float4 v = *reinterpret_cast<const float4*>(A + i);
  ushort4 h;
  h.x = f2h(v.x); h.y = f2h(v.y); h.z = f2h(v.z); h.w = f2h(v.w);
  *reinterpret_cast<ushort4*>(hi + i) = h;
}

__global__ __launch_bounds__(256) void k_bsum(const ushort* __restrict__ u, float* __restrict__ Sb) {
  int b = blockIdx.x, tid = threadIdx.x;
  int j0 = b * BS;
  int w = (BS < T_DIM - j0) ? BS : (T_DIM - j0);
  int c = tid * 4;
  float4 acc = {0,0,0,0};
  for (int j = 0; j < w; ++j) {
    ushort4 v = *reinterpret_cast<const ushort4*>(u + (size_t)(j0 + j) * D_DIM + c);
    acc.x += h2f(v.x); acc.y += h2f(v.y); acc.z += h2f(v.z); acc.w += h2f(v.w);
  }
  *reinterpret_cast<float4*>(Sb + (size_t)b * D_DIM + c) = acc;
}

__global__ __launch_bounds__(256) void k_gsum(const float* __restrict__ Sb, float* __restrict__ S) {
  int c = blockIdx.x * 256 + threadIdx.x;
  float s = 0.f;
  for (int b = 0; b < NBLK; ++b) s += Sb[(size_t)b * D_DIM + c];
  S[c] = s;
}

// ---------------------------------------------------------------------------
// Fused QKV GEMM (fp16): Q,K 2-term; V 1-term.  (R11-proven, untouched.)
__global__ __launch_bounds__(256,2) void k_qkv(
    const ushort* __restrict__ xhi, const ushort* __restrict__ xlo,
    const ushort* __restrict__ Wqh, const ushort* __restrict__ Wkh,
    const ushort* __restrict__ Wvh,
    ushort* __restrict__ Qhi, ushort* __restrict__ Qlo,
    ushort* __restrict__ Khi, ushort* __restrict__ Vb) {
  __shared__ __align__(16) ushort lds[28672];
  const int tid = threadIdx.x;
  const int w = tid >> 6, lane = tid & 63;
  const int wr = w >> 1, wc = w & 1;
  const int g = lane >> 4, cl = lane & 15;
  const int i0 = blockIdx.y * 128, j0 = blockIdx.x * 64;

  int adA[4], adB[2];
#pragma unroll
  for (int is = 0; is < 4; ++is) {
    int r = wr*64 + is*16 + cl;
    adA[is] = r*32 + (g ^ ((r >> 1) & 3))*8;
  }
#pragma unroll
  for (int js = 0; js < 2; ++js) {
    int r = wc*32 + js*16 + cl;
    adB[js] = r*32 + (g ^ ((r >> 1) & 3))*8;
  }
  const int ra1 = tid >> 2, ra2 = 64 + (tid >> 2), rbr = tid >> 2;
  const int sa = tid & 3;
  const int wA1 = ra1*32 + (sa ^ ((ra1 >> 1) & 3))*8;
  const int wA2 = ra2*32 + (sa ^ ((ra2 >> 1) & 3))*8;
  const int wB  = rbr*32 + (sa ^ ((rbr >> 1) & 3))*8;
  const size_t gA1 = (size_t)(i0 + ra1) * D_DIM + sa*8;
  const size_t gA2 = (size_t)(i0 + ra2) * D_DIM + sa*8;
  const size_t gB  = (size_t)(j0 + rbr) * D_DIM + sa*8;

  f32x4 accQ[4][2], accK[4][2], accV[4][2];
#pragma unroll
  for (int is = 0; is < 4; ++is)
#pragma unroll
    for (int js = 0; js < 2; ++js) {
      accQ[is][js] = (f32x4){0.f,0.f,0.f,0.f};
      accK[is][js] = (f32x4){0.f,0.f,0.f,0.f};
      accV[is][js] = (f32x4){0.f,0.f,0.f,0.f};
    }

  short8 sXh1 = *reinterpret_cast<const short8*>(xhi + gA1);
  short8 sXh2 = *reinterpret_cast<const short8*>(xhi + gA2);
  short8 sXl1 = *reinterpret_cast<const short8*>(xlo + gA1);
  short8 sXl2 = *reinterpret_cast<const short8*>(xlo + gA2);
  short8 sQh  = *reinterpret_cast<const short8*>(Wqh + gB);
  short8 sKh  = *reinterpret_cast<const short8*>(Wkh + gB);
  short8 sVh  = *reinterpret_cast<const short8*>(Wvh + gB);

  for (int ks = 0; ks < 32; ++ks) {
    const int bofs = (ks & 1) * 14336;
    *reinterpret_cast<short8*>(&lds[bofs + wA1])          = sXh1;
    *reinterpret_cast<short8*>(&lds[bofs + wA2])          = sXh2;
    *reinterpret_cast<short8*>(&lds[bofs + 4096 + wA1])   = sXl1;
    *reinterpret_cast<short8*>(&lds[bofs + 4096 + wA2])   = sXl2;
    *reinterpret_cast<short8*>(&lds[bofs + 8192 + wB])    = sQh;
    *reinterpret_cast<short8*>(&lds[bofs + 10240 + wB])   = sKh;
    *reinterpret_cast<short8*>(&lds[bofs + 12288 + wB])   = sVh;
    __syncthreads();
    short8 aH[4], aL[4], bQh[2], bKh[2], bVh[2];
#pragma unroll
    for (int is = 0; is < 4; ++is) {
      aH[is] = *reinterpret_cast<const short8*>(&lds[bofs + adA[is]]);
      aL[is] = *reinterpret_cast<const short8*>(&lds[bofs + 4096 + adA[is]]);
    }
#pragma unroll
    for (int js = 0; js < 2; ++js) {
      bQh[js] = *reinterpret_cast<const short8*>(&lds[bofs + 8192  + adB[js]]);
      bKh[js] = *reinterpret_cast<const short8*>(&lds[bofs + 10240 + adB[js]]);
      bVh[js] = *reinterpret_cast<const short8*>(&lds[bofs + 12288 + adB[js]]);
    }
    if (ks < 31) {
      const int k0 = (ks + 1) * 32;
      sXh1 = *reinterpret_cast<const short8*>(xhi + gA1 + k0);
      sXh2 = *reinterpret_cast<const short8*>(xhi + gA2 + k0);
      sXl1 = *reinterpret_cast<const short8*>(xlo + gA1 + k0);
      sXl2 = *reinterpret_cast<const short8*>(xlo + gA2 + k0);
      sQh  = *reinterpret_cast<const short8*>(Wqh + gB + k0);
      sKh  = *reinterpret_cast<const short8*>(Wkh + gB + k0);
      sVh  = *reinterpret_cast<const short8*>(Wvh + gB + k0);
    }
#pragma unroll
    for (int js = 0; js < 2; ++js)
#pragma unroll
      for (int is = 0; is < 4; ++is) {
        accQ[is][js] = MFMAH(aH[is], bQh[js], accQ[is][js]);
        accQ[is][js] = MFMAH(aL[is], bQh[js], accQ[is][js]);
        accK[is][js] = MFMAH(aH[is], bKh[js], accK[is][js]);
        accK[is][js] = MFMAH(aL[is], bKh[js], accK[is][js]);
        accV[is][js] = MFMAH(aH[is], bVh[js], accV[is][js]);
      }
  }
#pragma unroll
  for (int is = 0; is < 4; ++is)
#pragma unroll
    for (int js = 0; js < 2; ++js)
#pragma unroll
      for (int a = 0; a < 4; ++a) {
        int gi = i0 + wr*64 + is*16 + g*4 + a;
        int gj = j0 + wc*32 + js*16 + cl;
        size_t o = (size_t)gi*D_DIM + gj;
        float vq = accQ[is][js][a];
        ushort hq = f2h(vq);
        Qhi[o] = hq; Qlo[o] = f2h(vq - h2f(hq));
        Khi[o] = f2h(accK[is][js][a]);
        Vb[o]  = f2h(accV[is][js][a]);
      }
}

// ---------------------------------------------------------------------------
// E = Q@K^T (fp16 2-term) -> PERMUTED tile-blob layout + row-max partials.
// Blob wg at E + wg*32768 floats; thread stores acc[is][js] (f32x4) at
// (((w*4+is)*8+js)*64 + lane)*4 -- fully coalesced, 32 f32x4 stores/thread
// (vs 128 scattered dwords row-major).  k_D reads the same layout back.
__global__ __launch_bounds__(256,2) void k_E(
    const ushort* __restrict__ Qhi, const ushort* __restrict__ Qlo,
    const ushort* __restrict__ Khi,
    float* __restrict__ E, float* __restrict__ pm) {
  __shared__ __align__(16) ushort lds[32768]; // dbuf 16384: Qhi@0 Qlo@4096 (128x32) | Khi@8192 (256x32)
  __shared__ float stat_s[2][2][64];
  const int tid = threadIdx.x;
  const int bid = blockIdx.x;
  const int wg = (bid & 7) * 64 + (bid >> 3);   // XCD-bijective (512 % 8 == 0)
  const int it = wg >> 4, chunk = wg & 15;
  const int i0 = it * 128, jb = chunk * 256;
  const int w = tid >> 6, lane = tid & 63;
  const int wr = w >> 1, wc = w & 1;
  const int g = lane >> 4, cl = lane & 15;

  int adA[4], adB[8];
#pragma unroll
  for (int is = 0; is < 4; ++is) {
    int r = wr*64 + is*16 + cl;
    adA[is] = r*32 + (g ^ ((r >> 1) & 3))*8;
  }
#pragma unroll
  for (int js = 0; js < 8; ++js) {
    int r = wc*128 + js*16 + cl;
    adB[js] = 8192 + r*32 + (g ^ ((r >> 1) & 3))*8;
  }
  const int ra1 = tid >> 2, ra2 = 64 + (tid >> 2);
  const int sa = tid & 3;
  const int wA1 = ra1*32 + (sa ^ ((ra1 >> 1) & 3))*8;
  const int wA2 = ra2*32 + (sa ^ ((ra2 >> 1) & 3))*8;
  const size_t gA1 = (size_t)(i0 + ra1) * D_DIM + sa*8;
  const size_t gA2 = (size_t)(i0 + ra2) * D_DIM + sa*8;
  int wBo[4];
  size_t gBo[4];
#pragma unroll
  for (int r = 0; r < 4; ++r) {
    int rb = r*64 + (tid >> 2);
    wBo[r] = 8192 + rb*32 + (sa ^ ((rb >> 1) & 3))*8;
    gBo[r] = (size_t)(jb + rb) * D_DIM + sa*8;
  }

  f32x4 acc[4][8];
#pragma unroll
  for (int is = 0; is < 4; ++is)
#pragma unroll
    for (int js = 0; js < 8; ++js) acc[is][js] = (f32x4){0.f,0.f,0.f,0.f};

  short8 sQ1 = *reinterpret_cast<const short8*>(Qhi + gA1);
  short8 sQ2 = *reinterpret_cast<const short8*>(Qhi + gA2);
  short8 sq1 = *reinterpret_cast<const short8*>(Qlo + gA1);
  short8 sq2 = *reinterpret_cast<const short8*>(Qlo + gA2);
  short8 sK0 = *reinterpret_cast<const short8*>(Khi + gBo[0]);
  short8 sK1 = *reinterpret_cast<const short8*>(Khi + gBo[1]);
  short8 sK2 = *reinterpret_cast<const short8*>(Khi + gBo[2]);
  short8 sK3 = *reinterpret_cast<const short8*>(Khi + gBo[3]);

  for (int ks = 0; ks < 32; ++ks) {
    const int bofs = (ks & 1) * 16384;
    *reinterpret_cast<short8*>(&lds[bofs + wA1])        = sQ1;
    *reinterpret_cast<short8*>(&lds[bofs + wA2])        = sQ2;
    *reinterpret_cast<short8*>(&lds[bofs + 4096 + wA1]) = sq1;
    *reinterpret_cast<short8*>(&lds[bofs + 4096 + wA2]) = sq2;
    *reinterpret_cast<short8*>(&lds[bofs + wBo[0]])     = sK0;
    *reinterpret_cast<short8*>(&lds[bofs + wBo[1]])     = sK1;
    *reinterpret_cast<short8*>(&lds[bofs + wBo[2]])     = sK2;
    *reinterpret_cast<short8*>(&lds[bofs + wBo[3]])     = sK3;
    __syncthreads();
    short8 aQh[4], aQl[4];
#pragma unroll
    for (int is = 0; is < 4; ++is) {
      aQh[is] = *reinterpret_cast<const short8*>(&lds[bofs + adA[is]]);
      aQl[is] = *reinterpret_cast<const short8*>(&lds[bofs + 4096 + adA[is]]);
    }
    if (ks < 31) {
      const int k0 = (ks + 1) * 32;
      sQ1 = *reinterpret_cast<const short8*>(Qhi + gA1 + k0);
      sQ2 = *reinterpret_cast<const short8*>(Qhi + gA2 + k0);
      sq1 = *reinterpret_cast<const short8*>(Qlo + gA1 + k0);
      sq2 = *reinterpret_cast<const short8*>(Qlo + gA2 + k0);
      sK0 = *reinterpret_cast<const short8*>(Khi + gBo[0] + k0);
      sK1 = *reinterpret_cast<const short8*>(Khi + gBo[1] + k0);
      sK2 = *reinterpret_cast<const short8*>(Khi + gBo[2] + k0);
      sK3 = *reinterpret_cast<const short8*>(Khi + gBo[3] + k0);
    }
#pragma unroll
    for (int js = 0; js < 8; ++js) {
      short8 bK = *reinterpret_cast<const short8*>(&lds[bofs + adB[js]]);
#pragma unroll
      for (int is = 0; is < 4; ++is) {
        acc[is][js] = MFMAH(aQh[is], bK, acc[is][js]);
        acc[is][js] = MFMAH(aQl[is], bK, acc[is][js]);
      }
    }
  }
  // store permuted E blob (coalesced f32x4) + row-max partials
  float* blob = E + (size_t)wg * 32768;
#pragma unroll
  for (int is = 0; is < 4; ++is)
#pragma unroll
    for (int js = 0; js < 8; ++js)
      *reinterpret_cast<f32x4*>(blob + ((((size_t)w*4 + is)*8 + js)*64 + lane)*4) = acc[is][js];
#pragma unroll
  for (int is = 0; is < 4; ++is)
#pragma unroll
    for (int a = 0; a < 4; ++a) {
      float mx = -3.0e38f;
#pragma unroll
      for (int js = 0; js < 8; ++js) mx = fmaxf(mx, acc[is][js][a]);
#pragma unroll
      for (int mk = 1; mk < 16; mk <<= 1) mx = fmaxf(mx, __shfl_xor(mx, mk));
      if (cl == 0) stat_s[wr][wc][is*16 + g*4 + a] = mx;
    }
  __syncthreads();
  if (tid < 128) {
    int rl = tid & 63, wr2 = tid >> 6;
    pm[(size_t)chunk*T_DIM + i0 + wr2*64 + rl] =
        fmaxf(stat_s[wr2][0][rl], stat_s[wr2][1][rl]);
  }
}

__global__ __launch_bounds__(256) void k_rowmax(const float* __restrict__ pm, float* __restrict__ mrow) {
  int i = blockIdx.x * 256 + threadIdx.x;
  float m = -3.0e38f;
  for (int c = 0; c < NPART; ++c) m = fmaxf(m, pm[(size_t)c*T_DIM + i]);
  mrow[i] = m;
}

// ---------------------------------------------------------------------------
// D = U@U^T (fp16 1-term) + p=exp(e-m) stats + diag stash + own-blob zero.
// Reads E blob in the exact layout k_E wrote (same grid/wave decomposition),
// f32x4 loads; zero-fills its OWN contiguous blob (exclusive ownership, all
// reads complete before the barrier -> no cross-block race; blobs partition
// the 64MB att region exactly).
__global__ __launch_bounds__(256,2) void k_D(
    const ushort* __restrict__ Uh, float* __restrict__ E,
    const float* __restrict__ mrow,
    float* __restrict__ eb, float* __restrict__ db,
    float* __restrict__ pZ, float* __restrict__ pWe, float* __restrict__ pWd) {
  __shared__ __align__(16) ushort lds[24576]; // dbuf 12288: Ui@0 (128x32) | Uj@4096 (256x32)
  __shared__ float stat_s[2][2][64][3];
  const int tid = threadIdx.x;
  const int bid = blockIdx.x;
  const int wg = (bid & 7) * 64 + (bid >> 3);
  const int it = wg >> 4, chunk = wg & 15;
  const int i0 = it * 128, jb = chunk * 256;
  const int w = tid >> 6, lane = tid & 63;
  const int wr = w >> 1, wc = w & 1;
  const int g = lane >> 4, cl = lane & 15;

  int adA[4], adB[8];
#pragma unroll
  for (int is = 0; is < 4; ++is) {
    int r = wr*64 + is*16 + cl;
    adA[is] = r*32 + (g ^ ((r >> 1) & 3))*8;
  }
#pragma unroll
  for (int js = 0; js < 8; ++js) {
    int r = wc*128 + js*16 + cl;
    adB[js] = 4096 + r*32 + (g ^ ((r >> 1) & 3))*8;
  }
  const int ra1 = tid >> 2, ra2 = 64 + (tid >> 2);
  const int sa = tid & 3;
  const int wA1 = ra1*32 + (sa ^ ((ra1 >> 1) & 3))*8;
  const int wA2 = ra2*32 + (sa ^ ((ra2 >> 1) & 3))*8;
  const size_t gA1 = (size_t)(i0 + ra1) * D_DIM + sa*8;
  const size_t gA2 = (size_t)(i0 + ra2) * D_DIM + sa*8;
  int wBo[4];
  size_t gBo[4];
#pragma unroll
  for (int r = 0; r < 4; ++r) {
    int rb = r*64 + (tid >> 2);
    wBo[r] = 4096 + rb*32 + (sa ^ ((rb >> 1) & 3))*8;
    gBo[r] = (size_t)(jb + rb) * D_DIM + sa*8;
  }

  f32x4 acc[4][8];
#pragma unroll
  for (int is = 0; is < 4; ++is)
#pragma unroll
    for (int js = 0; js < 8; ++js) acc[is][js] = (f32x4){0.f,0.f,0.f,0.f};

  short8 sU1 = *reinterpret_cast<const short8*>(Uh + gA1);
  short8 sU2 = *reinterpret_cast<const short8*>(Uh + gA2);
  short8 sV0 = *reinterpret_cast<const short8*>(Uh + gBo[0]);
  short8 sV1 = *reinterpret_cast<const short8*>(Uh + gBo[1]);
  short8 sV2 = *reinterpret_cast<const short8*>(Uh + gBo[2]);
  short8 sV3 = *reinterpret_cast<const short8*>(Uh + gBo[3]);

  for (int ks = 0; ks < 32; ++ks) {
    const int bofs = (ks & 1) * 12288;
    *reinterpret_cast<short8*>(&lds[bofs + wA1])    = sU1;
    *reinterpret_cast<short8*>(&lds[bofs + wA2])    = sU2;
    *reinterpret_cast<short8*>(&lds[bofs + wBo[0]]) = sV0;
    *reinterpret_cast<short8*>(&lds[bofs + wBo[1]]) = sV1;
    *reinterpret_cast<short8*>(&lds[bofs + wBo[2]]) = sV2;
    *reinterpret_cast<short8*>(&lds[bofs + wBo[3]]) = sV3;
    __syncthreads();
    short8 aU[4];
#pragma unroll
    for (int is = 0; is < 4; ++is)
      aU[is] = *reinterpret_cast<const short8*>(&lds[bofs + adA[is]]);
    if (ks < 31) {
      const int k0 = (ks + 1) * 32;
      sU1 = *reinterpret_cast<const short8*>(Uh + gA1 + k0);
      sU2 = *reinterpret_cast<const short8*>(Uh + gA2 + k0);
      sV0 = *reinterpret_cast<const short8*>(Uh + gBo[0] + k0);
      sV1 = *reinterpret_cast<const short8*>(Uh + gBo[1] + k0);
      sV2 = *reinterpret_cast<const short8*>(Uh + gBo[2] + k0);
      sV3 = *reinterpret_cast<const short8*>(Uh + gBo[3] + k0);
    }
#pragma unroll
    for (int js = 0; js < 8; ++js) {
      short8 bU = *reinterpret_cast<const short8*>(&lds[bofs + adB[js]]);
#pragma unroll
      for (int is = 0; is < 4; ++is)
        acc[is][js] = MFMAH(aU[is], bU, acc[is][js]);
    }
  }

  // epilogue: read E blob (f32x4), p = exp(e - m), partials + diag stash
  const int iw0 = i0 + wr*64;
  const int blkLo = iw0 / BS, blkHi = (iw0 + 63) / BS;
  const int jw0 = jb + wc*128;
  const bool doDiag = (jw0 < (blkHi+1)*BS) && (jw0 + 128 > blkLo*BS);
  const float* blob = E + (size_t)wg * 32768;

#pragma unroll
  for (int is = 0; is < 4; ++is) {
    float mreg[4], z[4], we[4], wd[4];
#pragma unroll
    for (int a = 0; a < 4; ++a) {
      mreg[a] = mrow[i0 + wr*64 + is*16 + g*4 + a];
      z[a] = 0.f; we[a] = 0.f; wd[a] = 0.f;
    }
#pragma unroll
    for (int js = 0; js < 8; ++js) {
      f32x4 e4 = *reinterpret_cast<const f32x4*>(blob + ((((size_t)w*4 + is)*8 + js)*64 + lane)*4);
      int gj = jb + wc*128 + js*16 + cl;
#pragma unroll
      for (int a = 0; a < 4; ++a) {
        float e = e4[a];
        float d = acc[is][js][a];
        float p = __expf(e - mreg[a]);
        z[a] += p; we[a] += p*e; wd[a] += p*d;
        if (doDiag) {
          int gi = i0 + wr*64 + is*16 + g*4 + a;
          int bi = gi / BS;
          if (gj / BS == bi) {
            int c = gj - bi * BS;
            eb[(size_t)gi*64 + c] = e;
            db[(size_t)gi*64 + c] = d;
          }
        }
      }
    }
#pragma unroll
    for (int a = 0; a < 4; ++a) {
      float zz = z[a], ww = we[a], dd = wd[a];
#pragma unroll
      for (int mk = 1; mk < 16; mk <<= 1) {
        zz += __shfl_xor(zz, mk); ww += __shfl_xor(ww, mk); dd += __shfl_xor(dd, mk);
      }
      if (cl == 0) {
        int rl = is*16 + g*4 + a;
        stat_s[wr][wc][rl][0] = zz;
        stat_s[wr][wc][rl][1] = ww;
        stat_s[wr][wc][rl][2] = dd;
      }
    }
  }
  __syncthreads();   // all blob reads complete block-wide
  if (tid < 128) {
    int rl = tid & 63, wr2 = tid >> 6;
    size_t idx = (size_t)chunk*T_DIM + i0 + wr2*64 + rl;
    pZ[idx]  = stat_s[wr2][0][rl][0] + stat_s[wr2][1][rl][0];
    pWe[idx] = stat_s[wr2][0][rl][1] + stat_s[wr2][1][rl][1];
    pWd[idx] = stat_s[wr2][0][rl][2] + stat_s[wr2][1][rl][2];
  }
  // zero-fill OWN blob range (contiguous 128KB, exclusive ownership)
  float* blobw = E + (size_t)wg * 32768;
#pragma unroll
  for (int r = 0; r < 32; ++r)
    *reinterpret_cast<float4*>(blobw + ((size_t)r*256 + tid)*4) =
        (float4){0.f, 0.f, 0.f, 0.f};
}

// ---------------------------------------------------------------------------
__global__ __launch_bounds__(256) void k_merge(const float* __restrict__ pZ,
    const float* __restrict__ pWe, const float* __restrict__ pWd,
    const float* __restrict__ mrow,
    const ushort* __restrict__ Uh, const float* __restrict__ Sg, const float* __restrict__ Sb,
    const float* __restrict__ eb, const float* __restrict__ db,
    float* __restrict__ dep, float* __restrict__ ent, float* __restrict__ zrow) {
  int i = blockIdx.x, tid = threadIdx.x;
  float m = mrow[i];
  float Z = 0.f, We = 0.f, Wd = 0.f;
  for (int c = 0; c < NPART; ++c) {
    Z  += pZ [(size_t)c*T_DIM + i];
    We += pWe[(size_t)c*T_DIM + i];
    Wd += pWd[(size_t)c*T_DIM + i];
  }
  int b = i / BS, j0 = b * BS;
  int w = (BS < T_DIM - j0) ? BS : (T_DIM - j0);
  ushort4 uv = *reinterpret_cast<const ushort4*>(Uh + (size_t)i*D_DIM + tid*4);
  float4 Sv  = *reinterpret_cast<const float4*>(Sg + tid*4);
  float4 Sbv = *reinterpret_cast<const float4*>(Sb + (size_t)b*D_DIM + tid*4);
  float ux = h2f(uv.x), uy = h2f(uv.y), uz = h2f(uv.z), uw = h2f(uv.w);
  float dS  = ux*Sv.x  + uy*Sv.y  + uz*Sv.z  + uw*Sv.w;
  float dSb = ux*Sbv.x + uy*Sbv.y + uz*Sbv.z + uw*Sbv.w;
  float pb = 0.f, pdb = 0.f;
  if (tid < w) {
    float e = eb[(size_t)i*64 + tid], d = db[(size_t)i*64 + tid];
    float p = __expf(e - m);
    pb = p; pdb = p * d;
  }
  float v0 = dS, v1 = dSb, v2 = pb, v3 = pdb;
#pragma unroll
  for (int mk = 1; mk < 64; mk <<= 1) {
    v0 += __shfl_xor(v0, mk); v1 += __shfl_xor(v1, mk);
    v2 += __shfl_xor(v2, mk); v3 += __shfl_xor(v3, mk);
  }
  __shared__ float red[4][4];
  if ((tid & 63) == 0) { int wv = tid >> 6; red[0][wv]=v0; red[1][wv]=v1; red[2][wv]=v2; red[3][wv]=v3; }
  __syncthreads();
  if (tid == 0) {
    float tdS  = red[0][0]+red[0][1]+red[0][2]+red[0][3];
    float tdSb = red[1][0]+red[1][1]+red[1][2]+red[1][3];
    float s1   = red[2][0]+red[2][1]+red[2][2]+red[2][3];
    float s2   = red[3][0]+red[3][1]+red[3][2]+red[3][3];
    float invZ = 1.0f / Z;
    float num = (1.0f - s1*invZ) - (Wd - s2)*invZ;
    float den = (float)(T_DIM - w) - (tdS - tdSb);
    dep[i] = num / den;
    ent[i] = -(We*invZ - m - logf(Z)) / logf((float)T_DIM);
    zrow[i] = Z;
  }
}

__global__ __launch_bounds__(256) void k_entnorm(float* __restrict__ ent) {
  int tid = threadIdx.x;
  float s = 0.f;
  for (int i = tid; i < T_DIM; i += 256) s += fabsf(ent[i]);
#pragma unroll
  for (int mk = 1; mk < 64; mk <<= 1) s += __shfl_xor(s, mk);
  __shared__ float sb[4];
  if ((tid & 63) == 0) sb[tid >> 6] = s;
  __syncthreads();
  float inv = 1.0f / fmaxf(sb[0] + sb[1] + sb[2] + sb[3], 1e-12f);
  for (int i = tid; i < T_DIM; i += 256) ent[i] *= inv;
}

__global__ __launch_bounds__(256) void k_repack(const float* __restrict__ Wout, ushort* __restrict__ Wob) {
  int o = blockIdx.x;
  for (int k = threadIdx.x; k < 1024; k += 256)
    Wob[(size_t)o * 1024 + k] = f2h(Wout[(size_t)o * 1026 + k]);
}

// diag att write (att already zeroed by k_D) + y = att_win @ V.  (R15-proven.)
__global__ __launch_bounds__(256) void k_atty(const float* __restrict__ eb, const float* __restrict__ mrow,
    const float* __restrict__ zrow, const float* __restrict__ dep, const ushort* __restrict__ Vb,
    float* __restrict__ att, ushort* __restrict__ Ybf) {
  const int b  = blockIdx.x;
  const int cc = blockIdx.y & 3, rt = blockIdx.y >> 2;
  const int j0 = b * BS;
  const int w  = (BS < T_DIM - j0) ? BS : (T_DIM - j0);
  const int r0 = rt * 12;
  __shared__ float wl[12][BS + 1];
  __shared__ __align__(16) ushort vs[BS][256];
  const int tid = threadIdx.x;
  for (int idx = tid; idx < 12 * w; idx += 256) {
    int rr = idx / w, c = idx - rr * w;
    float val = 0.f;
    if (r0 + rr < w) {
      int gi = j0 + r0 + rr;
      val = __expf(eb[(size_t)gi * 64 + c] - mrow[gi]) / zrow[gi] + dep[j0 + c];
      if (cc == 0) att[(size_t)gi * T_DIM + j0 + c] = val;
    }
    wl[rr][c] = val;
  }
  const int ccol = cc * 256;
  for (int idx = tid; idx < w * 32; idx += 256) {
    int j = idx >> 5, s = idx & 31;
    *reinterpret_cast<short8*>(&vs[j][s * 8]) =
        *reinterpret_cast<const short8*>(&Vb[(size_t)(j0 + j) * D_DIM + ccol + s * 8]);
  }
  __syncthreads();
  float acc[12];
#pragma unroll
  for (int rr = 0; rr < 12; ++rr) acc[rr] = 0.f;
  for (int j = 0; j < w; ++j) {
    float v = h2f(vs[j][tid]);
#pragma unroll
    for (int rr = 0; rr < 12; ++rr)
      acc[rr] = fmaf(wl[rr][j], v, acc[rr]);
  }
#pragma unroll
  for (int rr = 0; rr < 12; ++rr)
    if (r0 + rr < w)
      Ybf[(size_t)(j0 + r0 + rr) * D_DIM + ccol + tid] = f2h(acc[rr]);
}

// ---------------------------------------------------------------------------
__global__ __launch_bounds__(256,4) void k_final(
    const ushort* __restrict__ Ybf, const ushort* __restrict__ Wob,
    const float* __restrict__ Wout, const float* __restrict__ ent,
    const float* __restrict__ dep, float* __restrict__ yout) {
  __shared__ ushort ldsB[8192];  // 2 x 4096
  const int tid = threadIdx.x;
  const int w = tid >> 6, lane = tid & 63;
  const int wr = w >> 1, wc = w & 1;
  const int g = lane >> 4, cl = lane & 15;
  const int i0 = blockIdx.y * 64, j0 = blockIdx.x * 64;
  f32x4 acc[2][2];
#pragma unroll
  for (int a = 0; a < 2; ++a)
#pragma unroll
    for (int b = 0; b < 2; ++b) acc[a][b] = (f32x4){0.f,0.f,0.f,0.f};
  const int ar0 = i0 + wr*32 + cl;

  const int r1 = tid >> 3, c1 = tid & 7;
  const int r2 = (tid + 256) >> 3, c2 = (tid + 256) & 7;
  const int lo1 = r1*64 + (c1 ^ (r1 & 7))*8;
  const int lo2 = r2*64 + (c2 ^ (r2 & 7))*8;
  const size_t gB1 = (size_t)(j0 + r1) * D_DIM + c1*8;
  const size_t gB2 = (size_t)(j0 + r2) * D_DIM + c2*8;

  short8 sB1 = *reinterpret_cast<const short8*>(Wob + gB1);
  short8 sB2 = *reinterpret_cast<const short8*>(Wob + gB2);
  short8 aY[2][2];
#pragma unroll
  for (int is = 0; is < 2; ++is)
#pragma unroll
    for (int h = 0; h < 2; ++h)
      aY[is][h] = *reinterpret_cast<const short8*>(Ybf + (size_t)(ar0 + is*16) * D_DIM + (h*4+g)*8);

  for (int ks = 0; ks < 16; ++ks) {
    const int bofs = (ks & 1) * 4096;
    *reinterpret_cast<short8*>(&ldsB[bofs + lo1]) = sB1;
    *reinterpret_cast<short8*>(&ldsB[bofs + lo2]) = sB2;
    __syncthreads();
    short8 aC[2][2];
#pragma unroll
    for (int is = 0; is < 2; ++is)
#pragma unroll
      for (int h = 0; h < 2; ++h) aC[is][h] = aY[is][h];
    if (ks < 15) {
      const int k0 = (ks + 1) * 64;
      sB1 = *reinterpret_cast<const short8*>(Wob + gB1 + k0);
      sB2 = *reinterpret_cast<const short8*>(Wob + gB2 + k0);
#pragma unroll
      for (int is = 0; is < 2; ++is)
#pragma unroll
        for (int h = 0; h < 2; ++h)
          aY[is][h] = *reinterpret_cast<const short8*>(Ybf + (size_t)(ar0 + is*16) * D_DIM + k0 + (h*4+g)*8);
    }
#pragma unroll
    for (int h = 0; h < 2; ++h)
#pragma unroll
      for (int js = 0; js < 2; ++js) {
        const int br = wc*32 + js*16 + cl;
        short8 bW = *reinterpret_cast<const short8*>(&ldsB[bofs + br*64 + ((h*4+g) ^ (br & 7))*8]);
#pragma unroll
        for (int is = 0; is < 2; ++is)
          acc[is][js] = MFMAH(aC[is][h], bW, acc[is][js]);
      }
  }
  float w1[2], w2[2];
#pragma unroll
  for (int js = 0; js < 2; ++js) {
    int gj = j0 + wc*32 + js*16 + cl;
    w1[js] = Wout[(size_t)gj * 1026 + 1024];
    w2[js] = Wout[(size_t)gj * 1026 + 1025];
  }
#pragma unroll
  for (int is = 0; is < 2; ++is)
#pragma unroll
    for (int a = 0; a < 4; ++a) {
      int gi = i0 + wr*32 + is*16 + g*4 + a;
      float e = ent[gi], d = dep[gi];
#pragma unroll
      for (int js = 0; js < 2; ++js) {
        int gj = j0 + wc*32 + js*16 + cl;
        yout[(size_t)gi * D_DIM + gj] = acc[is][js][a] + e * w1[js] + d * w2[js];
      }
    }
}

// ---------------------------------------------------------------------------
extern "C" void kernel_launch(void* const* d_in, const int* in_sizes, int n_in,
                              void* d_out, int out_size, void* d_ws, size_t ws_size,
                              hipStream_t stream) {
  const float* x    = (const float*)d_in[0];
  const float* Wk   = (const float*)d_in[1];
  const float* Wq   = (const float*)d_in[2];
  const float* Wv   = (const float*)d_in[3];
  const float* Wout = (const float*)d_in[4];
  float* out = (float*)d_out;
  char* wsb  = (char*)d_ws;

  ushort* Uh   = (ushort*)(wsb + 0);            // 8 MB (fp16)
  ushort* Vb   = (ushort*)(wsb + 8388608);      // 8 MB
  ushort* Wqh  = (ushort*)(wsb + 16777216);     // 2 MB
  ushort* Wkh  = (ushort*)(wsb + 18874368);     // 2 MB
  ushort* Wvh  = (ushort*)(wsb + 20971520);     // 2 MB
  ushort* Ybf  = (ushort*)(wsb + 23068672);     // 8 MB
  ushort* Wob  = (ushort*)(wsb + 31457280);     // 2 MB
  ushort* Khi  = (ushort*)(wsb + 33554432);     // 8 MB
  ushort* xhi  = (ushort*)(wsb + 41943040);     // 8 MB
  ushort* xlo  = (ushort*)(wsb + 50331648);     // 8 MB
  // x-zone aliases (valid after k_qkv)
  float*  eb   = (float*)(wsb + 41943040);      // 1 MB
  float*  db   = (float*)(wsb + 42991616);      // 1 MB
  float*  pZ   = (float*)(wsb + 44040192);      // 0.5 MB each
  float*  pWe  = (float*)(wsb + 44564480);
  float*  pWd  = (float*)(wsb + 45088768);
  float*  pm   = (float*)(wsb + 45613056);
  float*  Sb   = (float*)(wsb + 46137344);      // 283 KB
  float*  Sg   = (float*)(wsb + 46428160);      // 4 KB
  float*  mrow = (float*)(wsb + 46432256);      // 16 KB each
  float*  zrow = (float*)(wsb + 46448640);
  float*  ent  = (float*)(wsb + 46465024);
  float*  dep  = (float*)(wsb + 46481408);

  float* yout = out;                               // [4096][1024]
  float* att  = out + (size_t)T_DIM * D_DIM;       // [4096][4096] = E blobs then att
  ushort* Qhi = (ushort*)yout;                     // Q splits live in yout until k_E done
  ushort* Qlo = Qhi + 4194304;
  float*  E   = att;

  k_prep<<<T_DIM, 256, 0, stream>>>(x, xhi, xlo, Uh);
  k_wsplit<<<dim3(1024, 3), 256, 0, stream>>>(Wq, Wk, Wv, Wqh, Wkh, Wvh);
  k_qkv<<<dim3(16, 32), 256, 0, stream>>>(xhi, xlo, Wqh, Wkh, Wvh,
                                          Qhi, Qlo, Khi, Vb);
  k_bsum<<<NBLK, 256, 0, stream>>>(Uh, Sb);
  k_gsum<<<4, 256, 0, stream>>>(Sb, Sg);

  k_E<<<512, 256, 0, stream>>>(Qhi, Qlo, Khi, E, pm);
  k_rowmax<<<16, 256, 0, stream>>>(pm, mrow);
  k_D<<<512, 256, 0, stream>>>(Uh, E, mrow, eb, db, pZ, pWe, pWd);
  k_merge<<<T_DIM, 256, 0, stream>>>(pZ, pWe, pWd, mrow, Uh, Sg, Sb, eb, db, dep, ent, zrow);
  k_entnorm<<<1, 256, 0, stream>>>(ent);

  k_repack<<<1024, 256, 0, stream>>>(Wout, Wob);
  k_atty<<<dim3(NBLK, 20), 256, 0, stream>>>(eb, mrow, zrow, dep, Vb, att, Ybf);
  k_final<<<dim3(16, 64), 256, 0, stream>>>(Ybf, Wob, Wout, ent, dep, yout);
}